// Round 1
// baseline (1719.455 us; speedup 1.0000x reference)
//
#include <hip/hip_runtime.h>

#define D 128
#define NG 32
#define NC 10

// ---------------- degree ----------------
__global__ void degree_kernel(const int* __restrict__ src, const int* __restrict__ dst,
                              int* __restrict__ cout_, int* __restrict__ cin_, int E) {
  int e = blockIdx.x * 256 + threadIdx.x;
  if (e < E) {
    atomicAdd(&cout_[src[e]], 1);
    atomicAdd(&cin_[dst[e]], 1);
  }
}

__global__ void inv_kernel(const int* __restrict__ cout_, const int* __restrict__ cin_,
                           float* __restrict__ iout, float* __restrict__ iin, int n) {
  int i = blockIdx.x * 256 + threadIdx.x;
  if (i < n) {
    iout[i] = rsqrtf(fmaxf((float)cout_[i], 1.f));
    iin[i]  = rsqrtf(fmaxf((float)cin_[i], 1.f));
  }
}

// ---------------- scan (exclusive prefix sum of in-degree -> rowptr) ----------------
// chunk = 1024 elements per block, 256 threads x 4 elems
__global__ void scan1_kernel(const int* __restrict__ cnt, int* __restrict__ bsum, int n) {
  __shared__ int sdata[256];
  int base = blockIdx.x * 1024 + threadIdx.x * 4;
  int s = 0;
#pragma unroll
  for (int j = 0; j < 4; ++j) {
    int idx = base + j;
    if (idx < n) s += cnt[idx];
  }
  sdata[threadIdx.x] = s;
  __syncthreads();
  for (int off = 128; off > 0; off >>= 1) {
    if (threadIdx.x < off) sdata[threadIdx.x] += sdata[threadIdx.x + off];
    __syncthreads();
  }
  if (threadIdx.x == 0) bsum[blockIdx.x] = sdata[0];
}

__global__ void scan2_kernel(int* __restrict__ bsum, int nb) {
  if (blockIdx.x == 0 && threadIdx.x == 0) {
    int acc = 0;
    for (int i = 0; i < nb; ++i) { int v = bsum[i]; bsum[i] = acc; acc += v; }
  }
}

__global__ void scan3_kernel(const int* __restrict__ cnt, const int* __restrict__ bsum,
                             int* __restrict__ rowptr, int n, int e_total) {
  __shared__ int ss[256];
  int t = threadIdx.x;
  int idx0 = blockIdx.x * 1024 + t * 4;
  int v[4]; int ts = 0;
#pragma unroll
  for (int j = 0; j < 4; ++j) {
    v[j] = (idx0 + j < n) ? cnt[idx0 + j] : 0;
    ts += v[j];
  }
  ss[t] = ts;
  __syncthreads();
  for (int off = 1; off < 256; off <<= 1) {
    int add = 0;
    if (t >= off) add = ss[t - off];
    __syncthreads();
    if (t >= off) ss[t] += add;
    __syncthreads();
  }
  int excl = ss[t] - ts + bsum[blockIdx.x];
#pragma unroll
  for (int j = 0; j < 4; ++j) {
    int idx = idx0 + j;
    if (idx < n) rowptr[idx] = excl;
    excl += v[j];
  }
  if (blockIdx.x == 0 && t == 0) rowptr[n] = e_total;
}

__global__ void fill_kernel(const int* __restrict__ src, const int* __restrict__ dst,
                            const int* __restrict__ rowptr, int* __restrict__ cursor,
                            int* __restrict__ csrc, int E) {
  int e = blockIdx.x * 256 + threadIdx.x;
  if (e < E) {
    int d_ = dst[e];
    int pos = rowptr[d_] + atomicAdd(&cursor[d_], 1);
    csrc[pos] = src[e];
  }
}

// ---------------- aggregation: y[i] = inv_in[i] * sum_{e in CSR(i)} inv_out[s]*x[s] ----------------
__global__ __launch_bounds__(256) void agg_kernel(const float* __restrict__ x,
    const int* __restrict__ rowptr, const int* __restrict__ csrc,
    const float* __restrict__ iout, const float* __restrict__ iin,
    float* __restrict__ y, int n) {
  int node = blockIdx.x * 4 + (threadIdx.x >> 6);
  if (node >= n) return;
  int lane = threadIdx.x & 63;
  int beg = rowptr[node], end = rowptr[node + 1];
  float ax = 0.f, ay = 0.f;
  const float* xp = x + (size_t)(lane * 2);
  int e = beg;
  for (; e + 4 <= end; e += 4) {
    int s0 = csrc[e], s1 = csrc[e + 1], s2 = csrc[e + 2], s3 = csrc[e + 3];
    float w0 = iout[s0], w1 = iout[s1], w2 = iout[s2], w3 = iout[s3];
    float2 v0 = *(const float2*)(xp + (size_t)s0 * D);
    float2 v1 = *(const float2*)(xp + (size_t)s1 * D);
    float2 v2 = *(const float2*)(xp + (size_t)s2 * D);
    float2 v3 = *(const float2*)(xp + (size_t)s3 * D);
    ax += w0 * v0.x; ay += w0 * v0.y;
    ax += w1 * v1.x; ay += w1 * v1.y;
    ax += w2 * v2.x; ay += w2 * v2.y;
    ax += w3 * v3.x; ay += w3 * v3.y;
  }
  for (; e < end; ++e) {
    int s = csrc[e];
    float w = iout[s];
    float2 v = *(const float2*)(xp + (size_t)s * D);
    ax += w * v.x; ay += w * v.y;
  }
  float wi = iin[node];
  float2 r; r.x = ax * wi; r.y = ay * wi;
  *(float2*)(y + (size_t)node * D + lane * 2) = r;
}

// ---------------- fp32 GEMM + bias + relu: Y[n,128] = relu(A[n,128] @ W[128,128] + b) ----------------
// In-place safe (Y may alias A): each block stages its 64-row tile in LDS before writing.
__global__ __launch_bounds__(256) void gemm_bias_relu(const float* __restrict__ A,
    const float* __restrict__ W, const float* __restrict__ b,
    float* __restrict__ Y, int n) {
  __shared__ float As[64][132];
  int row0 = blockIdx.x * 64;
  for (int i = threadIdx.x; i < 64 * 32; i += 256) {
    int r = i >> 5, c4 = (i & 31) * 4;
    int row = row0 + r;
    float4 v = make_float4(0.f, 0.f, 0.f, 0.f);
    if (row < n) v = *(const float4*)(A + (size_t)row * D + c4);
    *(float4*)&As[r][c4] = v;
  }
  __syncthreads();
  int cg = threadIdx.x & 31, rg = threadIdx.x >> 5;
  int col = cg * 4;
  float4 acc[8];
#pragma unroll
  for (int r = 0; r < 8; ++r) acc[r] = make_float4(0.f, 0.f, 0.f, 0.f);
  for (int k = 0; k < D; k += 4) {
    float4 w0 = *(const float4*)(W + (size_t)k * D + col);
    float4 w1 = *(const float4*)(W + (size_t)(k + 1) * D + col);
    float4 w2 = *(const float4*)(W + (size_t)(k + 2) * D + col);
    float4 w3 = *(const float4*)(W + (size_t)(k + 3) * D + col);
#pragma unroll
    for (int r = 0; r < 8; ++r) {
      float4 a = *(const float4*)&As[rg * 8 + r][k];
      acc[r].x += a.x * w0.x + a.y * w1.x + a.z * w2.x + a.w * w3.x;
      acc[r].y += a.x * w0.y + a.y * w1.y + a.z * w2.y + a.w * w3.y;
      acc[r].z += a.x * w0.z + a.y * w1.z + a.z * w2.z + a.w * w3.z;
      acc[r].w += a.x * w0.w + a.y * w1.w + a.z * w2.w + a.w * w3.w;
    }
  }
  float4 bb = *(const float4*)(b + col);
#pragma unroll
  for (int r = 0; r < 8; ++r) {
    int row = row0 + rg * 8 + r;
    if (row < n) {
      float4 o;
      o.x = fmaxf(acc[r].x + bb.x, 0.f);
      o.y = fmaxf(acc[r].y + bb.y, 0.f);
      o.z = fmaxf(acc[r].z + bb.z, 0.f);
      o.w = fmaxf(acc[r].w + bb.w, 0.f);
      *(float4*)(Y + (size_t)row * D + col) = o;
    }
  }
}

// ---------------- pooling: sums[g][d] over sorted graph_ids ----------------
__device__ int lower_bound_gid(const int* gid, int n, int g) {
  int lo = 0, hi = n;
  while (lo < hi) { int mid = (lo + hi) >> 1; if (gid[mid] < g) lo = mid + 1; else hi = mid; }
  return lo;
}

__global__ void pool_kernel(const float* __restrict__ x, const int* __restrict__ gid,
                            float* __restrict__ sums, int* __restrict__ counts, int n) {
  int g = blockIdx.x >> 3, part = blockIdx.x & 7;
  __shared__ int s_lo, s_hi;
  if (threadIdx.x == 0) {
    s_lo = lower_bound_gid(gid, n, g);
    s_hi = lower_bound_gid(gid, n, g + 1);
    if (part == 0) counts[g] = s_hi - s_lo;
  }
  __syncthreads();
  int lo = s_lo, hi = s_hi;
  int cnt = hi - lo;
  int per = (cnt + 7) >> 3;
  int a = lo + part * per;
  int bnd = min(a + per, hi);
  int t = threadIdx.x;
  float acc = 0.f;
  for (int i = a; i < bnd; ++i) acc += x[(size_t)i * D + t];
  atomicAdd(&sums[g * D + t], acc);
}

// ---------------- classifier: out = relu(hg@Wc1+bc1) @ Wc2 + bc2 ----------------
__global__ __launch_bounds__(128) void classifier_kernel(const float* __restrict__ sums,
    const int* __restrict__ counts, const float* __restrict__ Wc1, const float* __restrict__ bc1,
    const float* __restrict__ Wc2, const float* __restrict__ bc2, float* __restrict__ out) {
  __shared__ float hg[NG][D];
  __shared__ float hid[NG][D];
  int t = threadIdx.x;
#pragma unroll
  for (int g = 0; g < NG; ++g)
    hg[g][t] = sums[g * D + t] / fmaxf((float)counts[g], 1.f);
  __syncthreads();
  float acc[NG];
#pragma unroll
  for (int g = 0; g < NG; ++g) acc[g] = bc1[t];
  for (int k = 0; k < D; ++k) {
    float w = Wc1[k * D + t];
#pragma unroll
    for (int g = 0; g < NG; ++g) acc[g] += hg[g][k] * w;
  }
#pragma unroll
  for (int g = 0; g < NG; ++g) hid[g][t] = fmaxf(acc[g], 0.f);
  __syncthreads();
  for (int idx = t; idx < NG * NC; idx += 128) {
    int g = idx / NC, c = idx % NC;
    float a = bc2[c];
    for (int j = 0; j < D; ++j) a += hid[g][j] * Wc2[j * NC + c];
    out[idx] = a;
  }
}

extern "C" void kernel_launch(void* const* d_in, const int* in_sizes, int n_in,
                              void* d_out, int out_size, void* d_ws, size_t ws_size,
                              hipStream_t stream) {
  const float* h   = (const float*)d_in[0];
  const int* src   = (const int*)d_in[1];
  const int* dst   = (const int*)d_in[2];
  const int* gid   = (const int*)d_in[3];
  const float* W1  = (const float*)d_in[4];
  const float* b1  = (const float*)d_in[5];
  const float* W2  = (const float*)d_in[6];
  const float* b2  = (const float*)d_in[7];
  const float* W3  = (const float*)d_in[8];
  const float* b3  = (const float*)d_in[9];
  const float* W4  = (const float*)d_in[10];
  const float* b4  = (const float*)d_in[11];
  const float* Wc1 = (const float*)d_in[12];
  const float* bc1 = (const float*)d_in[13];
  const float* Wc2 = (const float*)d_in[14];
  const float* bc2 = (const float*)d_in[15];
  float* out = (float*)d_out;

  const int N = in_sizes[3];
  const int E = in_sizes[1];

  char* ws = (char*)d_ws;
  size_t off = 0;
  auto alloc = [&](size_t bytes) -> char* {
    char* p = ws + off;
    off = (off + bytes + 255) & ~(size_t)255;
    return p;
  };

  int* ints3   = (int*)alloc((size_t)3 * N * 4);   // count_out | count_in | cursor
  int* cout_   = ints3;
  int* cin_    = ints3 + N;
  int* cursor  = ints3 + 2 * N;
  float* iout  = (float*)alloc((size_t)N * 4);
  float* iin   = (float*)alloc((size_t)N * 4);
  int* rowptr  = (int*)alloc((size_t)(N + 1) * 4);
  int* bsum    = (int*)alloc(1024);
  int* csrc    = (int*)alloc((size_t)E * 4);
  float* bufA  = (float*)alloc((size_t)N * D * 4);
  float* bufB  = (float*)alloc((size_t)N * D * 4);
  float* sums  = (float*)alloc((size_t)(NG * D + NG) * 4);  // sums | counts
  int* counts  = (int*)(sums + NG * D);

  hipMemsetAsync(ints3, 0, (size_t)3 * N * 4, stream);
  hipMemsetAsync(sums, 0, (size_t)(NG * D + NG) * 4, stream);

  int gE = (E + 255) / 256;
  int gN = (N + 255) / 256;
  int nb = (N + 1023) / 1024;

  degree_kernel<<<gE, 256, 0, stream>>>(src, dst, cout_, cin_, E);
  inv_kernel<<<gN, 256, 0, stream>>>(cout_, cin_, iout, iin, N);
  scan1_kernel<<<nb, 256, 0, stream>>>(cin_, bsum, N);
  scan2_kernel<<<1, 64, 0, stream>>>(bsum, nb);
  scan3_kernel<<<nb, 256, 0, stream>>>(cin_, bsum, rowptr, N, E);
  fill_kernel<<<gE, 256, 0, stream>>>(src, dst, rowptr, cursor, csrc, E);

  int gAgg  = (N + 3) / 4;
  int gGemm = (N + 63) / 64;

  // layer 1: h -> bufA
  agg_kernel<<<gAgg, 256, 0, stream>>>(h, rowptr, csrc, iout, iin, bufA, N);
  gemm_bias_relu<<<gGemm, 256, 0, stream>>>(bufA, W1, b1, bufA, N);
  // layer 2: bufA -> bufB
  agg_kernel<<<gAgg, 256, 0, stream>>>(bufA, rowptr, csrc, iout, iin, bufB, N);
  gemm_bias_relu<<<gGemm, 256, 0, stream>>>(bufB, W2, b2, bufB, N);
  // layer 3: bufB -> bufA
  agg_kernel<<<gAgg, 256, 0, stream>>>(bufB, rowptr, csrc, iout, iin, bufA, N);
  gemm_bias_relu<<<gGemm, 256, 0, stream>>>(bufA, W3, b3, bufA, N);
  // layer 4: bufA -> bufB
  agg_kernel<<<gAgg, 256, 0, stream>>>(bufA, rowptr, csrc, iout, iin, bufB, N);
  gemm_bias_relu<<<gGemm, 256, 0, stream>>>(bufB, W4, b4, bufB, N);

  pool_kernel<<<NG * 8, 128, 0, stream>>>(bufB, gid, sums, counts, N);
  classifier_kernel<<<1, 128, 0, stream>>>(sums, counts, Wc1, bc1, Wc2, bc2, out);
}

// Round 2
// 1607.410 us; speedup vs baseline: 1.0697x; 1.0697x over previous
//
#include <hip/hip_runtime.h>

#define D 128
#define NG 32
#define NC 10

// ---------------- pass A: edge tickets + out-degree count, fused with X1 = h @ W1 ----------------
// Blocks [0, gE): edge pass.  Blocks [gE, gE+gG): 32-row GEMM tiles of h@W1 -> X1.
__global__ __launch_bounds__(256) void passA_kernel(
    const int* __restrict__ src, const int* __restrict__ dst,
    int* __restrict__ cout_, int* __restrict__ cursor, int* __restrict__ rank, int E,
    const float* __restrict__ h, const float* __restrict__ W1, float* __restrict__ X1,
    int n, int gE) {
  __shared__ float As[32][132];
  if ((int)blockIdx.x < gE) {
    int e = blockIdx.x * 256 + threadIdx.x;
    if (e < E) {
      int s = src[e], d_ = dst[e];
      rank[e] = atomicAdd(&cursor[d_], 1);
      atomicAdd(&cout_[s], 1);
    }
    return;
  }
  // GEMM part: 32-row tile
  int row0 = ((int)blockIdx.x - gE) * 32;
  for (int i = threadIdx.x; i < 32 * 32; i += 256) {
    int r = i >> 5, c4 = (i & 31) * 4;
    int row = row0 + r;
    float4 v = make_float4(0.f, 0.f, 0.f, 0.f);
    if (row < n) v = *(const float4*)(h + (size_t)row * D + c4);
    *(float4*)&As[r][c4] = v;
  }
  __syncthreads();
  int cg = threadIdx.x & 31, rg = threadIdx.x >> 5;
  int col = cg * 4;
  float4 acc[4];
#pragma unroll
  for (int r = 0; r < 4; ++r) acc[r] = make_float4(0.f, 0.f, 0.f, 0.f);
  for (int k = 0; k < D; k += 4) {
    float4 w0 = *(const float4*)(W1 + (size_t)k * D + col);
    float4 w1 = *(const float4*)(W1 + (size_t)(k + 1) * D + col);
    float4 w2 = *(const float4*)(W1 + (size_t)(k + 2) * D + col);
    float4 w3 = *(const float4*)(W1 + (size_t)(k + 3) * D + col);
#pragma unroll
    for (int r = 0; r < 4; ++r) {
      float4 a = *(const float4*)&As[rg * 4 + r][k];
      acc[r].x += a.x * w0.x + a.y * w1.x + a.z * w2.x + a.w * w3.x;
      acc[r].y += a.x * w0.y + a.y * w1.y + a.z * w2.y + a.w * w3.y;
      acc[r].z += a.x * w0.z + a.y * w1.z + a.z * w2.z + a.w * w3.z;
      acc[r].w += a.x * w0.w + a.y * w1.w + a.z * w2.w + a.w * w3.w;
    }
  }
#pragma unroll
  for (int r = 0; r < 4; ++r) {
    int row = row0 + rg * 4 + r;
    if (row < n) *(float4*)(X1 + (size_t)row * D + col) = acc[r];
  }
}

__global__ void inv_kernel(const int* __restrict__ cout_, const int* __restrict__ cin_,
                           float* __restrict__ iout, float* __restrict__ iin, int n) {
  int i = blockIdx.x * 256 + threadIdx.x;
  if (i < n) {
    iout[i] = rsqrtf(fmaxf((float)cout_[i], 1.f));
    iin[i]  = rsqrtf(fmaxf((float)cin_[i], 1.f));
  }
}

// ---------------- scan (exclusive prefix sum of in-degree -> rowptr) ----------------
__global__ void scan1_kernel(const int* __restrict__ cnt, int* __restrict__ bsum, int n) {
  __shared__ int sdata[256];
  int base = blockIdx.x * 1024 + threadIdx.x * 4;
  int s = 0;
#pragma unroll
  for (int j = 0; j < 4; ++j) {
    int idx = base + j;
    if (idx < n) s += cnt[idx];
  }
  sdata[threadIdx.x] = s;
  __syncthreads();
  for (int off = 128; off > 0; off >>= 1) {
    if (threadIdx.x < off) sdata[threadIdx.x] += sdata[threadIdx.x + off];
    __syncthreads();
  }
  if (threadIdx.x == 0) bsum[blockIdx.x] = sdata[0];
}

__global__ void scan2_kernel(int* __restrict__ bsum, int nb) {
  if (blockIdx.x == 0 && threadIdx.x == 0) {
    int acc = 0;
    for (int i = 0; i < nb; ++i) { int v = bsum[i]; bsum[i] = acc; acc += v; }
  }
}

__global__ void scan3_kernel(const int* __restrict__ cnt, const int* __restrict__ bsum,
                             int* __restrict__ rowptr, int n, int e_total) {
  __shared__ int ss[256];
  int t = threadIdx.x;
  int idx0 = blockIdx.x * 1024 + t * 4;
  int v[4]; int ts = 0;
#pragma unroll
  for (int j = 0; j < 4; ++j) {
    v[j] = (idx0 + j < n) ? cnt[idx0 + j] : 0;
    ts += v[j];
  }
  ss[t] = ts;
  __syncthreads();
  for (int off = 1; off < 256; off <<= 1) {
    int add = 0;
    if (t >= off) add = ss[t - off];
    __syncthreads();
    if (t >= off) ss[t] += add;
    __syncthreads();
  }
  int excl = ss[t] - ts + bsum[blockIdx.x];
#pragma unroll
  for (int j = 0; j < 4; ++j) {
    int idx = idx0 + j;
    if (idx < n) rowptr[idx] = excl;
    excl += v[j];
  }
  if (blockIdx.x == 0 && t == 0) rowptr[n] = e_total;
}

// ---------------- pass B: atomic-free scatter into CSR ----------------
__global__ void passB_kernel(const int* __restrict__ src, const int* __restrict__ dst,
                             const int* __restrict__ rank, const int* __restrict__ rowptr,
                             int* __restrict__ csrc, int E) {
  int e = blockIdx.x * 256 + threadIdx.x;
  if (e < E) {
    int pos = rowptr[dst[e]] + rank[e];
    csrc[pos] = src[e];
  }
}

// ---------------- aggregation + bias + relu: y[i] = relu(iin[i]*sum_e iout[s]*x[s] + b) ----------------
__global__ __launch_bounds__(256) void agg_relu_kernel(const float* __restrict__ x,
    const int* __restrict__ rowptr, const int* __restrict__ csrc,
    const float* __restrict__ iout, const float* __restrict__ iin,
    const float* __restrict__ bias, float* __restrict__ y, int n) {
  int node = blockIdx.x * 4 + (threadIdx.x >> 6);
  if (node >= n) return;
  int lane = threadIdx.x & 63;
  int beg = rowptr[node], end = rowptr[node + 1];
  float ax = 0.f, ay = 0.f;
  const float* xp = x + (size_t)(lane * 2);
  int e = beg;
  for (; e + 4 <= end; e += 4) {
    int s0 = csrc[e], s1 = csrc[e + 1], s2 = csrc[e + 2], s3 = csrc[e + 3];
    float w0 = iout[s0], w1 = iout[s1], w2 = iout[s2], w3 = iout[s3];
    float2 v0 = *(const float2*)(xp + (size_t)s0 * D);
    float2 v1 = *(const float2*)(xp + (size_t)s1 * D);
    float2 v2 = *(const float2*)(xp + (size_t)s2 * D);
    float2 v3 = *(const float2*)(xp + (size_t)s3 * D);
    ax += w0 * v0.x; ay += w0 * v0.y;
    ax += w1 * v1.x; ay += w1 * v1.y;
    ax += w2 * v2.x; ay += w2 * v2.y;
    ax += w3 * v3.x; ay += w3 * v3.y;
  }
  for (; e < end; ++e) {
    int s = csrc[e];
    float w = iout[s];
    float2 v = *(const float2*)(xp + (size_t)s * D);
    ax += w * v.x; ay += w * v.y;
  }
  float wi = iin[node];
  float bx = bias[lane * 2], by = bias[lane * 2 + 1];
  float2 r;
  r.x = fmaxf(ax * wi + bx, 0.f);
  r.y = fmaxf(ay * wi + by, 0.f);
  *(float2*)(y + (size_t)node * D + lane * 2) = r;
}

// ---------------- plain fp32 GEMM: Y[n,128] = A[n,128] @ W[128,128] (no bias/relu) ----------------
__global__ __launch_bounds__(256) void gemm_kernel(const float* __restrict__ A,
    const float* __restrict__ W, float* __restrict__ Y, int n) {
  __shared__ float As[64][132];
  int row0 = blockIdx.x * 64;
  for (int i = threadIdx.x; i < 64 * 32; i += 256) {
    int r = i >> 5, c4 = (i & 31) * 4;
    int row = row0 + r;
    float4 v = make_float4(0.f, 0.f, 0.f, 0.f);
    if (row < n) v = *(const float4*)(A + (size_t)row * D + c4);
    *(float4*)&As[r][c4] = v;
  }
  __syncthreads();
  int cg = threadIdx.x & 31, rg = threadIdx.x >> 5;
  int col = cg * 4;
  float4 acc[8];
#pragma unroll
  for (int r = 0; r < 8; ++r) acc[r] = make_float4(0.f, 0.f, 0.f, 0.f);
  for (int k = 0; k < D; k += 4) {
    float4 w0 = *(const float4*)(W + (size_t)k * D + col);
    float4 w1 = *(const float4*)(W + (size_t)(k + 1) * D + col);
    float4 w2 = *(const float4*)(W + (size_t)(k + 2) * D + col);
    float4 w3 = *(const float4*)(W + (size_t)(k + 3) * D + col);
#pragma unroll
    for (int r = 0; r < 8; ++r) {
      float4 a = *(const float4*)&As[rg * 8 + r][k];
      acc[r].x += a.x * w0.x + a.y * w1.x + a.z * w2.x + a.w * w3.x;
      acc[r].y += a.x * w0.y + a.y * w1.y + a.z * w2.y + a.w * w3.y;
      acc[r].z += a.x * w0.z + a.y * w1.z + a.z * w2.z + a.w * w3.z;
      acc[r].w += a.x * w0.w + a.y * w1.w + a.z * w2.w + a.w * w3.w;
    }
  }
#pragma unroll
  for (int r = 0; r < 8; ++r) {
    int row = row0 + rg * 8 + r;
    if (row < n) *(float4*)(Y + (size_t)row * D + col) = acc[r];
  }
}

// ---------------- pooling ----------------
__device__ int lower_bound_gid(const int* gid, int n, int g) {
  int lo = 0, hi = n;
  while (lo < hi) { int mid = (lo + hi) >> 1; if (gid[mid] < g) lo = mid + 1; else hi = mid; }
  return lo;
}

__global__ void pool_kernel(const float* __restrict__ x, const int* __restrict__ gid,
                            float* __restrict__ sums, int* __restrict__ counts, int n) {
  int g = blockIdx.x >> 3, part = blockIdx.x & 7;
  __shared__ int s_lo, s_hi;
  if (threadIdx.x == 0) {
    s_lo = lower_bound_gid(gid, n, g);
    s_hi = lower_bound_gid(gid, n, g + 1);
    if (part == 0) counts[g] = s_hi - s_lo;
  }
  __syncthreads();
  int lo = s_lo, hi = s_hi;
  int cnt = hi - lo;
  int per = (cnt + 7) >> 3;
  int a = lo + part * per;
  int bnd = min(a + per, hi);
  int t = threadIdx.x;
  float acc = 0.f;
  for (int i = a; i < bnd; ++i) acc += x[(size_t)i * D + t];
  atomicAdd(&sums[g * D + t], acc);
}

// ---------------- classifier ----------------
__global__ __launch_bounds__(128) void classifier_kernel(const float* __restrict__ sums,
    const int* __restrict__ counts, const float* __restrict__ Wc1, const float* __restrict__ bc1,
    const float* __restrict__ Wc2, const float* __restrict__ bc2, float* __restrict__ out) {
  __shared__ float hg[NG][D];
  __shared__ float hid[NG][D];
  int t = threadIdx.x;
#pragma unroll
  for (int g = 0; g < NG; ++g)
    hg[g][t] = sums[g * D + t] / fmaxf((float)counts[g], 1.f);
  __syncthreads();
  float acc[NG];
#pragma unroll
  for (int g = 0; g < NG; ++g) acc[g] = bc1[t];
  for (int k = 0; k < D; ++k) {
    float w = Wc1[k * D + t];
#pragma unroll
    for (int g = 0; g < NG; ++g) acc[g] += hg[g][k] * w;
  }
#pragma unroll
  for (int g = 0; g < NG; ++g) hid[g][t] = fmaxf(acc[g], 0.f);
  __syncthreads();
  for (int idx = t; idx < NG * NC; idx += 128) {
    int g = idx / NC, c = idx % NC;
    float a = bc2[c];
    for (int j = 0; j < D; ++j) a += hid[g][j] * Wc2[j * NC + c];
    out[idx] = a;
  }
}

extern "C" void kernel_launch(void* const* d_in, const int* in_sizes, int n_in,
                              void* d_out, int out_size, void* d_ws, size_t ws_size,
                              hipStream_t stream) {
  const float* h   = (const float*)d_in[0];
  const int* src   = (const int*)d_in[1];
  const int* dst   = (const int*)d_in[2];
  const int* gid   = (const int*)d_in[3];
  const float* W1  = (const float*)d_in[4];
  const float* b1  = (const float*)d_in[5];
  const float* W2  = (const float*)d_in[6];
  const float* b2  = (const float*)d_in[7];
  const float* W3  = (const float*)d_in[8];
  const float* b3  = (const float*)d_in[9];
  const float* W4  = (const float*)d_in[10];
  const float* b4  = (const float*)d_in[11];
  const float* Wc1 = (const float*)d_in[12];
  const float* bc1 = (const float*)d_in[13];
  const float* Wc2 = (const float*)d_in[14];
  const float* bc2 = (const float*)d_in[15];
  float* out = (float*)d_out;

  const int N = in_sizes[3];
  const int E = in_sizes[1];

  char* ws = (char*)d_ws;
  size_t off = 0;
  auto alloc = [&](size_t bytes) -> char* {
    char* p = ws + off;
    off = (off + bytes + 255) & ~(size_t)255;
    return p;
  };

  int* cnts    = (int*)alloc((size_t)2 * N * 4);   // cout | cursor(->cin)
  int* cout_   = cnts;
  int* cursor  = cnts + N;
  float* iout  = (float*)alloc((size_t)N * 4);
  float* iin   = (float*)alloc((size_t)N * 4);
  int* rowptr  = (int*)alloc((size_t)(N + 1) * 4);
  int* bsum    = (int*)alloc(1024);
  int* csrc    = (int*)alloc((size_t)E * 4);
  float* bufA  = (float*)alloc((size_t)N * D * 4);  // X (gemm out)
  float* bufB  = (float*)alloc((size_t)N * D * 4);  // Y (agg out); first 4E bytes double as rank[]
  float* sums  = (float*)alloc((size_t)(NG * D + NG) * 4);
  int* counts  = (int*)(sums + NG * D);
  int* rank    = (int*)bufB;  // overlay: consumed by passB before bufB is first written

  hipMemsetAsync(cnts, 0, (size_t)2 * N * 4, stream);
  hipMemsetAsync(sums, 0, (size_t)(NG * D + NG) * 4, stream);

  int gE = (E + 255) / 256;
  int gN = (N + 255) / 256;
  int nb = (N + 1023) / 1024;
  int gG32 = (N + 31) / 32;

  // pass A: tickets + out-degree, fused with X1 = h@W1
  passA_kernel<<<gE + gG32, 256, 0, stream>>>(src, dst, cout_, cursor, rank, E,
                                              h, W1, bufA, N, gE);
  inv_kernel<<<gN, 256, 0, stream>>>(cout_, cursor, iout, iin, N);
  scan1_kernel<<<nb, 256, 0, stream>>>(cursor, bsum, N);
  scan2_kernel<<<1, 64, 0, stream>>>(bsum, nb);
  scan3_kernel<<<nb, 256, 0, stream>>>(cursor, bsum, rowptr, N, E);
  passB_kernel<<<gE, 256, 0, stream>>>(src, dst, rank, rowptr, csrc, E);

  int gAgg  = (N + 3) / 4;
  int gGemm = (N + 63) / 64;

  // layer 1: X1 (=h@W1, already in bufA) -> agg+b1+relu -> bufB
  agg_relu_kernel<<<gAgg, 256, 0, stream>>>(bufA, rowptr, csrc, iout, iin, b1, bufB, N);
  // layer 2
  gemm_kernel<<<gGemm, 256, 0, stream>>>(bufB, W2, bufA, N);
  agg_relu_kernel<<<gAgg, 256, 0, stream>>>(bufA, rowptr, csrc, iout, iin, b2, bufB, N);
  // layer 3
  gemm_kernel<<<gGemm, 256, 0, stream>>>(bufB, W3, bufA, N);
  agg_relu_kernel<<<gAgg, 256, 0, stream>>>(bufA, rowptr, csrc, iout, iin, b3, bufB, N);
  // layer 4
  gemm_kernel<<<gGemm, 256, 0, stream>>>(bufB, W4, bufA, N);
  agg_relu_kernel<<<gAgg, 256, 0, stream>>>(bufA, rowptr, csrc, iout, iin, b4, bufB, N);

  pool_kernel<<<NG * 8, 128, 0, stream>>>(bufB, gid, sums, counts, N);
  classifier_kernel<<<1, 128, 0, stream>>>(sums, counts, Wc1, bc1, Wc2, bc2, out);
}

// Round 3
// 1277.482 us; speedup vs baseline: 1.3460x; 1.2583x over previous
//
#include <hip/hip_runtime.h>

#define D 128
#define NG 32
#define NC 10

typedef unsigned short ushort_t;

__device__ __forceinline__ ushort_t f2bf(float x) {
  union { float f; unsigned u; } v; v.f = x;
  unsigned r = (v.u + 0x7FFF + ((v.u >> 16) & 1)) >> 16;
  return (ushort_t)r;
}
__device__ __forceinline__ float bf2f(ushort_t b) {
  union { unsigned u; float f; } v; v.u = ((unsigned)b) << 16;
  return v.f;
}

// ---------------- pass A: edge tickets + out-degree, fused with no-LDS gemm X1 = bf16(h @ W1) ----------------
__global__ __launch_bounds__(256, 8) void passA_kernel(
    const int* __restrict__ src, const int* __restrict__ dst,
    int* __restrict__ cout_, int* __restrict__ cursor, int* __restrict__ rank, int E,
    const float* __restrict__ h, const float* __restrict__ W1, ushort_t* __restrict__ X1,
    int n, int gE) {
  if ((int)blockIdx.x < gE) {
    int e = blockIdx.x * 256 + threadIdx.x;
    if (e < E) {
      int s = src[e], d_ = dst[e];
      rank[e] = atomicAdd(&cursor[d_], 1);
      atomicAdd(&cout_[s], 1);
    }
    return;
  }
  // register-tiled GEMM, no LDS: 32 rows x 128 cols per block; 4 rows x 4 cols per thread
  int row0 = ((int)blockIdx.x - gE) * 32;
  int cg = threadIdx.x & 31, rg = threadIdx.x >> 5;
  int col = cg * 4;
  int r0 = row0 + rg * 4;
  float4 acc[4];
#pragma unroll
  for (int r = 0; r < 4; ++r) acc[r] = make_float4(0.f, 0.f, 0.f, 0.f);
  const float* A0 = h + (size_t)r0 * D;
  bool full = (r0 + 4 <= n);
  for (int k = 0; k < D; k += 2) {
    float2 a[4];
    if (full) {
#pragma unroll
      for (int r = 0; r < 4; ++r) a[r] = *(const float2*)(A0 + (size_t)r * D + k);
    } else {
#pragma unroll
      for (int r = 0; r < 4; ++r)
        a[r] = (r0 + r < n) ? *(const float2*)(A0 + (size_t)r * D + k) : make_float2(0.f, 0.f);
    }
    float4 w0 = *(const float4*)(W1 + (size_t)k * D + col);
    float4 w1 = *(const float4*)(W1 + (size_t)(k + 1) * D + col);
#pragma unroll
    for (int r = 0; r < 4; ++r) {
      acc[r].x += a[r].x * w0.x + a[r].y * w1.x;
      acc[r].y += a[r].x * w0.y + a[r].y * w1.y;
      acc[r].z += a[r].x * w0.z + a[r].y * w1.z;
      acc[r].w += a[r].x * w0.w + a[r].y * w1.w;
    }
  }
#pragma unroll
  for (int r = 0; r < 4; ++r) {
    int row = r0 + r;
    if (row < n) {
      ushort_t o[4] = { f2bf(acc[r].x), f2bf(acc[r].y), f2bf(acc[r].z), f2bf(acc[r].w) };
      *(uint2*)(X1 + (size_t)row * D + col) = *(const uint2*)o;
    }
  }
}

__global__ void inv_kernel(const int* __restrict__ cout_, const int* __restrict__ cin_,
                           float* __restrict__ iout, float* __restrict__ iin, int n) {
  int i = blockIdx.x * 256 + threadIdx.x;
  if (i < n) {
    iout[i] = rsqrtf(fmaxf((float)cout_[i], 1.f));
    iin[i]  = rsqrtf(fmaxf((float)cin_[i], 1.f));
  }
}

// ---------------- scan ----------------
__global__ void scan1_kernel(const int* __restrict__ cnt, int* __restrict__ bsum, int n) {
  __shared__ int sdata[256];
  int base = blockIdx.x * 1024 + threadIdx.x * 4;
  int s = 0;
#pragma unroll
  for (int j = 0; j < 4; ++j) {
    int idx = base + j;
    if (idx < n) s += cnt[idx];
  }
  sdata[threadIdx.x] = s;
  __syncthreads();
  for (int off = 128; off > 0; off >>= 1) {
    if (threadIdx.x < off) sdata[threadIdx.x] += sdata[threadIdx.x + off];
    __syncthreads();
  }
  if (threadIdx.x == 0) bsum[blockIdx.x] = sdata[0];
}

__global__ void scan2_kernel(int* __restrict__ bsum, int nb) {
  if (blockIdx.x == 0 && threadIdx.x == 0) {
    int acc = 0;
    for (int i = 0; i < nb; ++i) { int v = bsum[i]; bsum[i] = acc; acc += v; }
  }
}

__global__ void scan3_kernel(const int* __restrict__ cnt, const int* __restrict__ bsum,
                             int* __restrict__ rowptr, int n, int e_total) {
  __shared__ int ss[256];
  int t = threadIdx.x;
  int idx0 = blockIdx.x * 1024 + t * 4;
  int v[4]; int ts = 0;
#pragma unroll
  for (int j = 0; j < 4; ++j) {
    v[j] = (idx0 + j < n) ? cnt[idx0 + j] : 0;
    ts += v[j];
  }
  ss[t] = ts;
  __syncthreads();
  for (int off = 1; off < 256; off <<= 1) {
    int add = 0;
    if (t >= off) add = ss[t - off];
    __syncthreads();
    if (t >= off) ss[t] += add;
    __syncthreads();
  }
  int excl = ss[t] - ts + bsum[blockIdx.x];
#pragma unroll
  for (int j = 0; j < 4; ++j) {
    int idx = idx0 + j;
    if (idx < n) rowptr[idx] = excl;
    excl += v[j];
  }
  if (blockIdx.x == 0 && t == 0) rowptr[n] = e_total;
}

// ---------------- pass B: atomic-free scatter ----------------
__global__ void passB_kernel(const int* __restrict__ src, const int* __restrict__ dst,
                             const int* __restrict__ rank, const int* __restrict__ rowptr,
                             int* __restrict__ csrc, int E) {
  int e = blockIdx.x * 256 + threadIdx.x;
  if (e < E) {
    int pos = rowptr[dst[e]] + rank[e];
    csrc[pos] = src[e];
  }
}

// ---------------- aggregation (bf16 gather) + bias + relu -> fp32 ----------------
__global__ __launch_bounds__(256) void agg_relu_kernel(const ushort_t* __restrict__ x,
    const int* __restrict__ rowptr, const int* __restrict__ csrc,
    const float* __restrict__ iout, const float* __restrict__ iin,
    const float* __restrict__ bias, float* __restrict__ y, int n) {
  int node = blockIdx.x * 4 + (threadIdx.x >> 6);
  if (node >= n) return;
  int lane = threadIdx.x & 63;
  int beg = rowptr[node], end = rowptr[node + 1];
  float ax = 0.f, ay = 0.f;
  const ushort_t* xp = x + (size_t)(lane * 2);
  int e = beg;
  for (; e + 4 <= end; e += 4) {
    int s0 = csrc[e], s1 = csrc[e + 1], s2 = csrc[e + 2], s3 = csrc[e + 3];
    float w0 = iout[s0], w1 = iout[s1], w2 = iout[s2], w3 = iout[s3];
    ushort2 u0 = *(const ushort2*)(xp + (size_t)s0 * D);
    ushort2 u1 = *(const ushort2*)(xp + (size_t)s1 * D);
    ushort2 u2 = *(const ushort2*)(xp + (size_t)s2 * D);
    ushort2 u3 = *(const ushort2*)(xp + (size_t)s3 * D);
    ax += w0 * bf2f(u0.x); ay += w0 * bf2f(u0.y);
    ax += w1 * bf2f(u1.x); ay += w1 * bf2f(u1.y);
    ax += w2 * bf2f(u2.x); ay += w2 * bf2f(u2.y);
    ax += w3 * bf2f(u3.x); ay += w3 * bf2f(u3.y);
  }
  for (; e < end; ++e) {
    int s = csrc[e];
    float w = iout[s];
    ushort2 u = *(const ushort2*)(xp + (size_t)s * D);
    ax += w * bf2f(u.x); ay += w * bf2f(u.y);
  }
  float wi = iin[node];
  float bx = bias[lane * 2], by = bias[lane * 2 + 1];
  float2 r;
  r.x = fmaxf(ax * wi + bx, 0.f);
  r.y = fmaxf(ay * wi + by, 0.f);
  *(float2*)(y + (size_t)node * D + lane * 2) = r;
}

// ---------------- fp32 GEMM -> bf16 out: X[n,128] = bf16(A[n,128] @ W[128,128]) ----------------
__global__ __launch_bounds__(256) void gemm_kernel(const float* __restrict__ A,
    const float* __restrict__ W, ushort_t* __restrict__ Y, int n) {
  __shared__ float As[64][132];
  int row0 = blockIdx.x * 64;
  for (int i = threadIdx.x; i < 64 * 32; i += 256) {
    int r = i >> 5, c4 = (i & 31) * 4;
    int row = row0 + r;
    float4 v = make_float4(0.f, 0.f, 0.f, 0.f);
    if (row < n) v = *(const float4*)(A + (size_t)row * D + c4);
    *(float4*)&As[r][c4] = v;
  }
  __syncthreads();
  int cg = threadIdx.x & 31, rg = threadIdx.x >> 5;
  int col = cg * 4;
  float4 acc[8];
#pragma unroll
  for (int r = 0; r < 8; ++r) acc[r] = make_float4(0.f, 0.f, 0.f, 0.f);
  for (int k = 0; k < D; k += 4) {
    float4 w0 = *(const float4*)(W + (size_t)k * D + col);
    float4 w1 = *(const float4*)(W + (size_t)(k + 1) * D + col);
    float4 w2 = *(const float4*)(W + (size_t)(k + 2) * D + col);
    float4 w3 = *(const float4*)(W + (size_t)(k + 3) * D + col);
#pragma unroll
    for (int r = 0; r < 8; ++r) {
      float4 a = *(const float4*)&As[rg * 8 + r][k];
      acc[r].x += a.x * w0.x + a.y * w1.x + a.z * w2.x + a.w * w3.x;
      acc[r].y += a.x * w0.y + a.y * w1.y + a.z * w2.y + a.w * w3.y;
      acc[r].z += a.x * w0.z + a.y * w1.z + a.z * w2.z + a.w * w3.z;
      acc[r].w += a.x * w0.w + a.y * w1.w + a.z * w2.w + a.w * w3.w;
    }
  }
#pragma unroll
  for (int r = 0; r < 8; ++r) {
    int row = row0 + rg * 8 + r;
    if (row < n) {
      ushort_t o[4] = { f2bf(acc[r].x), f2bf(acc[r].y), f2bf(acc[r].z), f2bf(acc[r].w) };
      *(uint2*)(Y + (size_t)row * D + col) = *(const uint2*)o;
    }
  }
}

// ---------------- pooling ----------------
__device__ int lower_bound_gid(const int* gid, int n, int g) {
  int lo = 0, hi = n;
  while (lo < hi) { int mid = (lo + hi) >> 1; if (gid[mid] < g) lo = mid + 1; else hi = mid; }
  return lo;
}

__global__ void pool_kernel(const float* __restrict__ x, const int* __restrict__ gid,
                            float* __restrict__ sums, int* __restrict__ counts, int n) {
  int g = blockIdx.x >> 3, part = blockIdx.x & 7;
  __shared__ int s_lo, s_hi;
  if (threadIdx.x == 0) {
    s_lo = lower_bound_gid(gid, n, g);
    s_hi = lower_bound_gid(gid, n, g + 1);
    if (part == 0) counts[g] = s_hi - s_lo;
  }
  __syncthreads();
  int lo = s_lo, hi = s_hi;
  int cnt = hi - lo;
  int per = (cnt + 7) >> 3;
  int a = lo + part * per;
  int bnd = min(a + per, hi);
  int t = threadIdx.x;
  float acc = 0.f;
  for (int i = a; i < bnd; ++i) acc += x[(size_t)i * D + t];
  atomicAdd(&sums[g * D + t], acc);
}

// ---------------- classifier ----------------
__global__ __launch_bounds__(128) void classifier_kernel(const float* __restrict__ sums,
    const int* __restrict__ counts, const float* __restrict__ Wc1, const float* __restrict__ bc1,
    const float* __restrict__ Wc2, const float* __restrict__ bc2, float* __restrict__ out) {
  __shared__ float hg[NG][D];
  __shared__ float hid[NG][D];
  int t = threadIdx.x;
#pragma unroll
  for (int g = 0; g < NG; ++g)
    hg[g][t] = sums[g * D + t] / fmaxf((float)counts[g], 1.f);
  __syncthreads();
  float acc[NG];
#pragma unroll
  for (int g = 0; g < NG; ++g) acc[g] = bc1[t];
  for (int k = 0; k < D; ++k) {
    float w = Wc1[k * D + t];
#pragma unroll
    for (int g = 0; g < NG; ++g) acc[g] += hg[g][k] * w;
  }
#pragma unroll
  for (int g = 0; g < NG; ++g) hid[g][t] = fmaxf(acc[g], 0.f);
  __syncthreads();
  for (int idx = t; idx < NG * NC; idx += 128) {
    int g = idx / NC, c = idx % NC;
    float a = bc2[c];
    for (int j = 0; j < D; ++j) a += hid[g][j] * Wc2[j * NC + c];
    out[idx] = a;
  }
}

extern "C" void kernel_launch(void* const* d_in, const int* in_sizes, int n_in,
                              void* d_out, int out_size, void* d_ws, size_t ws_size,
                              hipStream_t stream) {
  const float* h   = (const float*)d_in[0];
  const int* src   = (const int*)d_in[1];
  const int* dst   = (const int*)d_in[2];
  const int* gid   = (const int*)d_in[3];
  const float* W1  = (const float*)d_in[4];
  const float* b1  = (const float*)d_in[5];
  const float* W2  = (const float*)d_in[6];
  const float* b2  = (const float*)d_in[7];
  const float* W3  = (const float*)d_in[8];
  const float* b3  = (const float*)d_in[9];
  const float* W4  = (const float*)d_in[10];
  const float* b4  = (const float*)d_in[11];
  const float* Wc1 = (const float*)d_in[12];
  const float* bc1 = (const float*)d_in[13];
  const float* Wc2 = (const float*)d_in[14];
  const float* bc2 = (const float*)d_in[15];
  float* out = (float*)d_out;

  const int N = in_sizes[3];
  const int E = in_sizes[1];

  char* ws = (char*)d_ws;
  size_t off = 0;
  auto alloc = [&](size_t bytes) -> char* {
    char* p = ws + off;
    off = (off + bytes + 255) & ~(size_t)255;
    return p;
  };

  int* cnts     = (int*)alloc((size_t)2 * N * 4);   // cout | cursor(->in-degree)
  int* cout_    = cnts;
  int* cursor   = cnts + N;
  float* iout   = (float*)alloc((size_t)N * 4);
  float* iin    = (float*)alloc((size_t)N * 4);
  int* rowptr   = (int*)alloc((size_t)(N + 1) * 4);
  int* bsum     = (int*)alloc(1024);
  int* csrc     = (int*)alloc((size_t)E * 4);
  ushort_t* Xb  = (ushort_t*)alloc((size_t)N * D * 2);  // bf16 pre-agg features
  float* Yb     = (float*)alloc((size_t)N * D * 4);     // fp32 agg output; head doubles as rank[]
  float* sums   = (float*)alloc((size_t)(NG * D + NG) * 4);
  int* counts   = (int*)(sums + NG * D);
  int* rank     = (int*)Yb;  // overlay: consumed by passB before Yb first written

  hipMemsetAsync(cnts, 0, (size_t)2 * N * 4, stream);
  hipMemsetAsync(sums, 0, (size_t)(NG * D + NG) * 4, stream);

  int gE = (E + 255) / 256;
  int gN = (N + 255) / 256;
  int nb = (N + 1023) / 1024;
  int gG32 = (N + 31) / 32;

  passA_kernel<<<gE + gG32, 256, 0, stream>>>(src, dst, cout_, cursor, rank, E,
                                              h, W1, Xb, N, gE);
  inv_kernel<<<gN, 256, 0, stream>>>(cout_, cursor, iout, iin, N);
  scan1_kernel<<<nb, 256, 0, stream>>>(cursor, bsum, N);
  scan2_kernel<<<1, 64, 0, stream>>>(bsum, nb);
  scan3_kernel<<<nb, 256, 0, stream>>>(cursor, bsum, rowptr, N, E);
  passB_kernel<<<gE, 256, 0, stream>>>(src, dst, rank, rowptr, csrc, E);

  int gAgg  = (N + 3) / 4;
  int gGemm = (N + 63) / 64;

  // layer 1: Xb (=bf16(h@W1)) -> agg+b1+relu -> Yb (fp32)
  agg_relu_kernel<<<gAgg, 256, 0, stream>>>(Xb, rowptr, csrc, iout, iin, b1, Yb, N);
  // layer 2
  gemm_kernel<<<gGemm, 256, 0, stream>>>(Yb, W2, Xb, N);
  agg_relu_kernel<<<gAgg, 256, 0, stream>>>(Xb, rowptr, csrc, iout, iin, b2, Yb, N);
  // layer 3
  gemm_kernel<<<gGemm, 256, 0, stream>>>(Yb, W3, Xb, N);
  agg_relu_kernel<<<gAgg, 256, 0, stream>>>(Xb, rowptr, csrc, iout, iin, b3, Yb, N);
  // layer 4
  gemm_kernel<<<gGemm, 256, 0, stream>>>(Yb, W4, Xb, N);
  agg_relu_kernel<<<gAgg, 256, 0, stream>>>(Xb, rowptr, csrc, iout, iin, b4, Yb, N);

  pool_kernel<<<NG * 8, 128, 0, stream>>>(Yb, gid, sums, counts, N);
  classifier_kernel<<<1, 128, 0, stream>>>(sums, counts, Wc1, bc1, Wc2, bc2, out);
}

// Round 4
// 1170.251 us; speedup vs baseline: 1.4693x; 1.0916x over previous
//
#include <hip/hip_runtime.h>

#define D 128
#define NG 32
#define NC 10

typedef unsigned short ushort_t;

__device__ __forceinline__ ushort_t f2bf(float x) {
  union { float f; unsigned u; } v; v.f = x;
  unsigned r = (v.u + 0x7FFF + ((v.u >> 16) & 1)) >> 16;
  return (ushort_t)r;
}
__device__ __forceinline__ float bf2f(ushort_t b) {
  union { unsigned u; float f; } v; v.u = ((unsigned)b) << 16;
  return v.f;
}

// ---------------- degree + tickets: 2 atomics/edge ----------------
__global__ void degree_kernel(const int* __restrict__ src, const int* __restrict__ dst,
                              int* __restrict__ cout_, int* __restrict__ cursor,
                              int* __restrict__ rank, int E) {
  int e = blockIdx.x * 256 + threadIdx.x;
  if (e < E) {
    int s = src[e], d_ = dst[e];
    rank[e] = atomicAdd(&cursor[d_], 1);
    atomicAdd(&cout_[s], 1);
  }
}

// ---------------- scan (exclusive prefix sum of in-degree -> rowptr) ----------------
__global__ void scan1_kernel(const int* __restrict__ cnt, int* __restrict__ bsum, int n) {
  __shared__ int sdata[256];
  int base = blockIdx.x * 1024 + threadIdx.x * 4;
  int s = 0;
#pragma unroll
  for (int j = 0; j < 4; ++j) {
    int idx = base + j;
    if (idx < n) s += cnt[idx];
  }
  sdata[threadIdx.x] = s;
  __syncthreads();
  for (int off = 128; off > 0; off >>= 1) {
    if (threadIdx.x < off) sdata[threadIdx.x] += sdata[threadIdx.x + off];
    __syncthreads();
  }
  if (threadIdx.x == 0) bsum[blockIdx.x] = sdata[0];
}

__global__ void scan2_kernel(int* __restrict__ bsum, int nb) {
  if (blockIdx.x == 0 && threadIdx.x == 0) {
    int acc = 0;
    for (int i = 0; i < nb; ++i) { int v = bsum[i]; bsum[i] = acc; acc += v; }
  }
}

__global__ void scan3_kernel(const int* __restrict__ cnt, const int* __restrict__ bsum,
                             int* __restrict__ rowptr, int n, int e_total) {
  __shared__ int ss[256];
  int t = threadIdx.x;
  int idx0 = blockIdx.x * 1024 + t * 4;
  int v[4]; int ts = 0;
#pragma unroll
  for (int j = 0; j < 4; ++j) {
    v[j] = (idx0 + j < n) ? cnt[idx0 + j] : 0;
    ts += v[j];
  }
  ss[t] = ts;
  __syncthreads();
  for (int off = 1; off < 256; off <<= 1) {
    int add = 0;
    if (t >= off) add = ss[t - off];
    __syncthreads();
    if (t >= off) ss[t] += add;
    __syncthreads();
  }
  int excl = ss[t] - ts + bsum[blockIdx.x];
#pragma unroll
  for (int j = 0; j < 4; ++j) {
    int idx = idx0 + j;
    if (idx < n) rowptr[idx] = excl;
    excl += v[j];
  }
  if (blockIdx.x == 0 && t == 0) rowptr[n] = e_total;
}

// ---------------- pass B: atomic-free scatter into CSR ----------------
__global__ void passB_kernel(const int* __restrict__ src, const int* __restrict__ dst,
                             const int* __restrict__ rank, const int* __restrict__ rowptr,
                             int* __restrict__ csrc, int E) {
  int e = blockIdx.x * 256 + threadIdx.x;
  if (e < E) {
    int pos = rowptr[dst[e]] + rank[e];
    csrc[pos] = src[e];
  }
}

// ---------------- GEMM (fp32 in) -> bf16 out, scaled by iout: X[i] = bf16(iout[i] * (A@W)[i]) ----------------
__global__ __launch_bounds__(256) void gemm_f32in_kernel(const float* __restrict__ A,
    const float* __restrict__ W, const int* __restrict__ cout_,
    ushort_t* __restrict__ X, int n) {
  __shared__ float As[64][132];
  int row0 = blockIdx.x * 64;
  for (int i = threadIdx.x; i < 64 * 32; i += 256) {
    int r = i >> 5, c4 = (i & 31) * 4;
    int row = row0 + r;
    float4 v = make_float4(0.f, 0.f, 0.f, 0.f);
    if (row < n) v = *(const float4*)(A + (size_t)row * D + c4);
    *(float4*)&As[r][c4] = v;
  }
  __syncthreads();
  int cg = threadIdx.x & 31, rg = threadIdx.x >> 5;
  int col = cg * 4;
  float4 acc[8];
#pragma unroll
  for (int r = 0; r < 8; ++r) acc[r] = make_float4(0.f, 0.f, 0.f, 0.f);
  for (int k = 0; k < D; k += 4) {
    float4 w0 = *(const float4*)(W + (size_t)k * D + col);
    float4 w1 = *(const float4*)(W + (size_t)(k + 1) * D + col);
    float4 w2 = *(const float4*)(W + (size_t)(k + 2) * D + col);
    float4 w3 = *(const float4*)(W + (size_t)(k + 3) * D + col);
#pragma unroll
    for (int r = 0; r < 8; ++r) {
      float4 a = *(const float4*)&As[rg * 8 + r][k];
      acc[r].x += a.x * w0.x + a.y * w1.x + a.z * w2.x + a.w * w3.x;
      acc[r].y += a.x * w0.y + a.y * w1.y + a.z * w2.y + a.w * w3.y;
      acc[r].z += a.x * w0.z + a.y * w1.z + a.z * w2.z + a.w * w3.z;
      acc[r].w += a.x * w0.w + a.y * w1.w + a.z * w2.w + a.w * w3.w;
    }
  }
#pragma unroll
  for (int r = 0; r < 8; ++r) {
    int row = row0 + rg * 8 + r;
    if (row < n) {
      float sc = rsqrtf(fmaxf((float)cout_[row], 1.f));
      ushort_t o[4] = { f2bf(acc[r].x * sc), f2bf(acc[r].y * sc),
                        f2bf(acc[r].z * sc), f2bf(acc[r].w * sc) };
      *(uint2*)(X + (size_t)row * D + col) = *(const uint2*)o;
    }
  }
}

// ---------------- GEMM (bf16 in) -> bf16 out, scaled by iout ----------------
__global__ __launch_bounds__(256) void gemm_bf16in_kernel(const ushort_t* __restrict__ A,
    const float* __restrict__ W, const int* __restrict__ cout_,
    ushort_t* __restrict__ X, int n) {
  __shared__ float As[64][132];
  int row0 = blockIdx.x * 64;
  for (int i = threadIdx.x; i < 64 * 32; i += 256) {
    int r = i >> 5, c4 = (i & 31) * 4;
    int row = row0 + r;
    float4 v = make_float4(0.f, 0.f, 0.f, 0.f);
    if (row < n) {
      ushort4 u = *(const ushort4*)(A + (size_t)row * D + c4);
      v.x = bf2f(u.x); v.y = bf2f(u.y); v.z = bf2f(u.z); v.w = bf2f(u.w);
    }
    *(float4*)&As[r][c4] = v;
  }
  __syncthreads();
  int cg = threadIdx.x & 31, rg = threadIdx.x >> 5;
  int col = cg * 4;
  float4 acc[8];
#pragma unroll
  for (int r = 0; r < 8; ++r) acc[r] = make_float4(0.f, 0.f, 0.f, 0.f);
  for (int k = 0; k < D; k += 4) {
    float4 w0 = *(const float4*)(W + (size_t)k * D + col);
    float4 w1 = *(const float4*)(W + (size_t)(k + 1) * D + col);
    float4 w2 = *(const float4*)(W + (size_t)(k + 2) * D + col);
    float4 w3 = *(const float4*)(W + (size_t)(k + 3) * D + col);
#pragma unroll
    for (int r = 0; r < 8; ++r) {
      float4 a = *(const float4*)&As[rg * 8 + r][k];
      acc[r].x += a.x * w0.x + a.y * w1.x + a.z * w2.x + a.w * w3.x;
      acc[r].y += a.x * w0.y + a.y * w1.y + a.z * w2.y + a.w * w3.y;
      acc[r].z += a.x * w0.z + a.y * w1.z + a.z * w2.z + a.w * w3.z;
      acc[r].w += a.x * w0.w + a.y * w1.w + a.z * w2.w + a.w * w3.w;
    }
  }
#pragma unroll
  for (int r = 0; r < 8; ++r) {
    int row = row0 + rg * 8 + r;
    if (row < n) {
      float sc = rsqrtf(fmaxf((float)cout_[row], 1.f));
      ushort_t o[4] = { f2bf(acc[r].x * sc), f2bf(acc[r].y * sc),
                        f2bf(acc[r].z * sc), f2bf(acc[r].w * sc) };
      *(uint2*)(X + (size_t)row * D + col) = *(const uint2*)o;
    }
  }
}

// ---------------- aggregation (bf16 gather, iout pre-folded) + bias + relu -> bf16 ----------------
__global__ __launch_bounds__(256) void agg_relu_kernel(const ushort_t* __restrict__ x,
    const int* __restrict__ rowptr, const int* __restrict__ csrc,
    const int* __restrict__ cin_, const float* __restrict__ bias,
    ushort_t* __restrict__ y, int n) {
  int node = blockIdx.x * 4 + (threadIdx.x >> 6);
  if (node >= n) return;
  int lane = threadIdx.x & 63;
  int beg = rowptr[node], end = rowptr[node + 1];
  float ax = 0.f, ay = 0.f;
  const ushort_t* xp = x + (size_t)(lane * 2);
  int e = beg;
  for (; e + 4 <= end; e += 4) {
    int s0 = csrc[e], s1 = csrc[e + 1], s2 = csrc[e + 2], s3 = csrc[e + 3];
    ushort2 u0 = *(const ushort2*)(xp + (size_t)s0 * D);
    ushort2 u1 = *(const ushort2*)(xp + (size_t)s1 * D);
    ushort2 u2 = *(const ushort2*)(xp + (size_t)s2 * D);
    ushort2 u3 = *(const ushort2*)(xp + (size_t)s3 * D);
    ax += bf2f(u0.x); ay += bf2f(u0.y);
    ax += bf2f(u1.x); ay += bf2f(u1.y);
    ax += bf2f(u2.x); ay += bf2f(u2.y);
    ax += bf2f(u3.x); ay += bf2f(u3.y);
  }
  for (; e < end; ++e) {
    int s = csrc[e];
    ushort2 u = *(const ushort2*)(xp + (size_t)s * D);
    ax += bf2f(u.x); ay += bf2f(u.y);
  }
  float wi = rsqrtf(fmaxf((float)cin_[node], 1.f));
  float2 bb = *(const float2*)(bias + lane * 2);
  ushort_t o[2] = { f2bf(fmaxf(ax * wi + bb.x, 0.f)), f2bf(fmaxf(ay * wi + bb.y, 0.f)) };
  *(unsigned*)(y + (size_t)node * D + lane * 2) = *(const unsigned*)o;
}

// ---------------- pooling (bf16 in) ----------------
__device__ int lower_bound_gid(const int* gid, int n, int g) {
  int lo = 0, hi = n;
  while (lo < hi) { int mid = (lo + hi) >> 1; if (gid[mid] < g) lo = mid + 1; else hi = mid; }
  return lo;
}

__global__ void pool_kernel(const ushort_t* __restrict__ x, const int* __restrict__ gid,
                            float* __restrict__ sums, int* __restrict__ counts, int n) {
  int g = blockIdx.x >> 3, part = blockIdx.x & 7;
  __shared__ int s_lo, s_hi;
  if (threadIdx.x == 0) {
    s_lo = lower_bound_gid(gid, n, g);
    s_hi = lower_bound_gid(gid, n, g + 1);
    if (part == 0) counts[g] = s_hi - s_lo;
  }
  __syncthreads();
  int lo = s_lo, hi = s_hi;
  int cnt = hi - lo;
  int per = (cnt + 7) >> 3;
  int a = lo + part * per;
  int bnd = min(a + per, hi);
  int t = threadIdx.x;
  float acc = 0.f;
  for (int i = a; i < bnd; ++i) acc += bf2f(x[(size_t)i * D + t]);
  atomicAdd(&sums[g * D + t], acc);
}

// ---------------- classifier ----------------
__global__ __launch_bounds__(128) void classifier_kernel(const float* __restrict__ sums,
    const int* __restrict__ counts, const float* __restrict__ Wc1, const float* __restrict__ bc1,
    const float* __restrict__ Wc2, const float* __restrict__ bc2, float* __restrict__ out) {
  __shared__ float hg[NG][D];
  __shared__ float hid[NG][D];
  int t = threadIdx.x;
#pragma unroll
  for (int g = 0; g < NG; ++g)
    hg[g][t] = sums[g * D + t] / fmaxf((float)counts[g], 1.f);
  __syncthreads();
  float acc[NG];
#pragma unroll
  for (int g = 0; g < NG; ++g) acc[g] = bc1[t];
  for (int k = 0; k < D; ++k) {
    float w = Wc1[k * D + t];
#pragma unroll
    for (int g = 0; g < NG; ++g) acc[g] += hg[g][k] * w;
  }
#pragma unroll
  for (int g = 0; g < NG; ++g) hid[g][t] = fmaxf(acc[g], 0.f);
  __syncthreads();
  for (int idx = t; idx < NG * NC; idx += 128) {
    int g = idx / NC, c = idx % NC;
    float a = bc2[c];
    for (int j = 0; j < D; ++j) a += hid[g][j] * Wc2[j * NC + c];
    out[idx] = a;
  }
}

extern "C" void kernel_launch(void* const* d_in, const int* in_sizes, int n_in,
                              void* d_out, int out_size, void* d_ws, size_t ws_size,
                              hipStream_t stream) {
  const float* h   = (const float*)d_in[0];
  const int* src   = (const int*)d_in[1];
  const int* dst   = (const int*)d_in[2];
  const int* gid   = (const int*)d_in[3];
  const float* W1  = (const float*)d_in[4];
  const float* b1  = (const float*)d_in[5];
  const float* W2  = (const float*)d_in[6];
  const float* b2  = (const float*)d_in[7];
  const float* W3  = (const float*)d_in[8];
  const float* b3  = (const float*)d_in[9];
  const float* W4  = (const float*)d_in[10];
  const float* b4  = (const float*)d_in[11];
  const float* Wc1 = (const float*)d_in[12];
  const float* bc1 = (const float*)d_in[13];
  const float* Wc2 = (const float*)d_in[14];
  const float* bc2 = (const float*)d_in[15];
  float* out = (float*)d_out;

  const int N = in_sizes[3];
  const int E = in_sizes[1];

  char* ws = (char*)d_ws;
  size_t off = 0;
  auto alloc = [&](size_t bytes) -> char* {
    char* p = ws + off;
    off = (off + bytes + 255) & ~(size_t)255;
    return p;
  };

  int* cnts     = (int*)alloc((size_t)2 * N * 4);   // cout | cursor(->in-degree)
  int* cout_    = cnts;
  int* cursor   = cnts + N;
  int* rowptr   = (int*)alloc((size_t)(N + 1) * 4);
  int* bsum     = (int*)alloc(1024);
  int* csrc     = (int*)alloc((size_t)E * 4);
  ushort_t* Xb  = (ushort_t*)alloc((size_t)N * D * 2);  // bf16 pre-agg (iout-scaled) features
  ushort_t* Yb  = (ushort_t*)alloc((size_t)N * D * 2);  // bf16 agg output; head doubles as rank[]
  float* sums   = (float*)alloc((size_t)(NG * D + NG) * 4);
  int* counts   = (int*)(sums + NG * D);
  int* rank     = (int*)Yb;  // overlay: consumed by passB before Yb first written

  hipMemsetAsync(cnts, 0, (size_t)2 * N * 4, stream);
  hipMemsetAsync(sums, 0, (size_t)(NG * D + NG) * 4, stream);

  int gE = (E + 255) / 256;
  int nb = (N + 1023) / 1024;
  int gAgg  = (N + 3) / 4;
  int gGemm = (N + 63) / 64;

  degree_kernel<<<gE, 256, 0, stream>>>(src, dst, cout_, cursor, rank, E);
  scan1_kernel<<<nb, 256, 0, stream>>>(cursor, bsum, N);
  scan2_kernel<<<1, 64, 0, stream>>>(bsum, nb);
  scan3_kernel<<<nb, 256, 0, stream>>>(cursor, bsum, rowptr, N, E);
  passB_kernel<<<gE, 256, 0, stream>>>(src, dst, rank, rowptr, csrc, E);

  // layer 1
  gemm_f32in_kernel<<<gGemm, 256, 0, stream>>>(h, W1, cout_, Xb, N);
  agg_relu_kernel<<<gAgg, 256, 0, stream>>>(Xb, rowptr, csrc, cursor, b1, Yb, N);
  // layer 2
  gemm_bf16in_kernel<<<gGemm, 256, 0, stream>>>(Yb, W2, cout_, Xb, N);
  agg_relu_kernel<<<gAgg, 256, 0, stream>>>(Xb, rowptr, csrc, cursor, b2, Yb, N);
  // layer 3
  gemm_bf16in_kernel<<<gGemm, 256, 0, stream>>>(Yb, W3, cout_, Xb, N);
  agg_relu_kernel<<<gAgg, 256, 0, stream>>>(Xb, rowptr, csrc, cursor, b3, Yb, N);
  // layer 4
  gemm_bf16in_kernel<<<gGemm, 256, 0, stream>>>(Yb, W4, cout_, Xb, N);
  agg_relu_kernel<<<gAgg, 256, 0, stream>>>(Xb, rowptr, csrc, cursor, b4, Yb, N);

  pool_kernel<<<NG * 8, 128, 0, stream>>>(Yb, gid, sums, counts, N);
  classifier_kernel<<<1, 128, 0, stream>>>(sums, counts, Wc1, bc1, Wc2, bc2, out);
}

// Round 5
// 1141.419 us; speedup vs baseline: 1.5064x; 1.0253x over previous
//
#include <hip/hip_runtime.h>

#define D 128
#define NG 32
#define NC 10

typedef unsigned short ushort_t;

__device__ __forceinline__ ushort_t f2bf(float x) {
  union { float f; unsigned u; } v; v.f = x;
  unsigned r = (v.u + 0x7FFF + ((v.u >> 16) & 1)) >> 16;
  return (ushort_t)r;
}
__device__ __forceinline__ float bf2f(ushort_t b) {
  union { unsigned u; float f; } v; v.u = ((unsigned)b) << 16;
  return v.f;
}

// ---------------- degree + tickets: 4 edges/thread, 8 atomics in flight ----------------
__global__ void degree_kernel(const int* __restrict__ src, const int* __restrict__ dst,
                              int* __restrict__ cout_, int* __restrict__ cursor,
                              int* __restrict__ rank, int E) {
  int i = blockIdx.x * 256 + threadIdx.x;
  int e0 = i * 4;
  if (e0 + 4 <= E) {
    int4 s = *(const int4*)(src + e0);
    int4 d_ = *(const int4*)(dst + e0);
    int r0 = atomicAdd(&cursor[d_.x], 1);
    int r1 = atomicAdd(&cursor[d_.y], 1);
    int r2 = atomicAdd(&cursor[d_.z], 1);
    int r3 = atomicAdd(&cursor[d_.w], 1);
    atomicAdd(&cout_[s.x], 1);
    atomicAdd(&cout_[s.y], 1);
    atomicAdd(&cout_[s.z], 1);
    atomicAdd(&cout_[s.w], 1);
    *(int4*)(rank + e0) = make_int4(r0, r1, r2, r3);
  } else {
    for (int e = e0; e < E; ++e) {
      rank[e] = atomicAdd(&cursor[dst[e]], 1);
      atomicAdd(&cout_[src[e]], 1);
    }
  }
}

// ---------------- scan ----------------
__global__ void scan1_kernel(const int* __restrict__ cnt, int* __restrict__ bsum, int n) {
  __shared__ int sdata[256];
  int base = blockIdx.x * 1024 + threadIdx.x * 4;
  int s = 0;
#pragma unroll
  for (int j = 0; j < 4; ++j) {
    int idx = base + j;
    if (idx < n) s += cnt[idx];
  }
  sdata[threadIdx.x] = s;
  __syncthreads();
  for (int off = 128; off > 0; off >>= 1) {
    if (threadIdx.x < off) sdata[threadIdx.x] += sdata[threadIdx.x + off];
    __syncthreads();
  }
  if (threadIdx.x == 0) bsum[blockIdx.x] = sdata[0];
}

__global__ void scan2_kernel(int* __restrict__ bsum, int nb) {
  if (blockIdx.x == 0 && threadIdx.x == 0) {
    int acc = 0;
    for (int i = 0; i < nb; ++i) { int v = bsum[i]; bsum[i] = acc; acc += v; }
  }
}

__global__ void scan3_kernel(const int* __restrict__ cnt, const int* __restrict__ bsum,
                             int* __restrict__ rowptr, int n, int e_total) {
  __shared__ int ss[256];
  int t = threadIdx.x;
  int idx0 = blockIdx.x * 1024 + t * 4;
  int v[4]; int ts = 0;
#pragma unroll
  for (int j = 0; j < 4; ++j) {
    v[j] = (idx0 + j < n) ? cnt[idx0 + j] : 0;
    ts += v[j];
  }
  ss[t] = ts;
  __syncthreads();
  for (int off = 1; off < 256; off <<= 1) {
    int add = 0;
    if (t >= off) add = ss[t - off];
    __syncthreads();
    if (t >= off) ss[t] += add;
    __syncthreads();
  }
  int excl = ss[t] - ts + bsum[blockIdx.x];
#pragma unroll
  for (int j = 0; j < 4; ++j) {
    int idx = idx0 + j;
    if (idx < n) rowptr[idx] = excl;
    excl += v[j];
  }
  if (blockIdx.x == 0 && t == 0) rowptr[n] = e_total;
}

// ---------------- pass B: atomic-free scatter, 4 edges/thread ----------------
__global__ void passB_kernel(const int* __restrict__ src, const int* __restrict__ dst,
                             const int* __restrict__ rank, const int* __restrict__ rowptr,
                             int* __restrict__ csrc, int E) {
  int i = blockIdx.x * 256 + threadIdx.x;
  int e0 = i * 4;
  if (e0 + 4 <= E) {
    int4 s = *(const int4*)(src + e0);
    int4 d_ = *(const int4*)(dst + e0);
    int4 r = *(const int4*)(rank + e0);
    csrc[rowptr[d_.x] + r.x] = s.x;
    csrc[rowptr[d_.y] + r.y] = s.y;
    csrc[rowptr[d_.z] + r.z] = s.z;
    csrc[rowptr[d_.w] + r.w] = s.w;
  } else {
    for (int e = e0; e < E; ++e)
      csrc[rowptr[dst[e]] + rank[e]] = src[e];
  }
}

// ---------------- GEMM (fp32 in) -> bf16 out, scaled by iout ----------------
__global__ __launch_bounds__(256) void gemm_f32in_kernel(const float* __restrict__ A,
    const float* __restrict__ W, const int* __restrict__ cout_,
    ushort_t* __restrict__ X, int n) {
  __shared__ float As[64][132];
  int row0 = blockIdx.x * 64;
  for (int i = threadIdx.x; i < 64 * 32; i += 256) {
    int r = i >> 5, c4 = (i & 31) * 4;
    int row = row0 + r;
    float4 v = make_float4(0.f, 0.f, 0.f, 0.f);
    if (row < n) v = *(const float4*)(A + (size_t)row * D + c4);
    *(float4*)&As[r][c4] = v;
  }
  __syncthreads();
  int cg = threadIdx.x & 31, rg = threadIdx.x >> 5;
  int col = cg * 4;
  float4 acc[8];
#pragma unroll
  for (int r = 0; r < 8; ++r) acc[r] = make_float4(0.f, 0.f, 0.f, 0.f);
  for (int k = 0; k < D; k += 4) {
    float4 w0 = *(const float4*)(W + (size_t)k * D + col);
    float4 w1 = *(const float4*)(W + (size_t)(k + 1) * D + col);
    float4 w2 = *(const float4*)(W + (size_t)(k + 2) * D + col);
    float4 w3 = *(const float4*)(W + (size_t)(k + 3) * D + col);
#pragma unroll
    for (int r = 0; r < 8; ++r) {
      float4 a = *(const float4*)&As[rg * 8 + r][k];
      acc[r].x += a.x * w0.x + a.y * w1.x + a.z * w2.x + a.w * w3.x;
      acc[r].y += a.x * w0.y + a.y * w1.y + a.z * w2.y + a.w * w3.y;
      acc[r].z += a.x * w0.z + a.y * w1.z + a.z * w2.z + a.w * w3.z;
      acc[r].w += a.x * w0.w + a.y * w1.w + a.z * w2.w + a.w * w3.w;
    }
  }
#pragma unroll
  for (int r = 0; r < 8; ++r) {
    int row = row0 + rg * 8 + r;
    if (row < n) {
      float sc = rsqrtf(fmaxf((float)cout_[row], 1.f));
      ushort_t o[4] = { f2bf(acc[r].x * sc), f2bf(acc[r].y * sc),
                        f2bf(acc[r].z * sc), f2bf(acc[r].w * sc) };
      *(uint2*)(X + (size_t)row * D + col) = *(const uint2*)o;
    }
  }
}

// ---------------- GEMM (bf16 in) -> bf16 out, scaled by iout ----------------
__global__ __launch_bounds__(256) void gemm_bf16in_kernel(const ushort_t* __restrict__ A,
    const float* __restrict__ W, const int* __restrict__ cout_,
    ushort_t* __restrict__ X, int n) {
  __shared__ float As[64][132];
  int row0 = blockIdx.x * 64;
  for (int i = threadIdx.x; i < 64 * 32; i += 256) {
    int r = i >> 5, c4 = (i & 31) * 4;
    int row = row0 + r;
    float4 v = make_float4(0.f, 0.f, 0.f, 0.f);
    if (row < n) {
      ushort4 u = *(const ushort4*)(A + (size_t)row * D + c4);
      v.x = bf2f(u.x); v.y = bf2f(u.y); v.z = bf2f(u.z); v.w = bf2f(u.w);
    }
    *(float4*)&As[r][c4] = v;
  }
  __syncthreads();
  int cg = threadIdx.x & 31, rg = threadIdx.x >> 5;
  int col = cg * 4;
  float4 acc[8];
#pragma unroll
  for (int r = 0; r < 8; ++r) acc[r] = make_float4(0.f, 0.f, 0.f, 0.f);
  for (int k = 0; k < D; k += 4) {
    float4 w0 = *(const float4*)(W + (size_t)k * D + col);
    float4 w1 = *(const float4*)(W + (size_t)(k + 1) * D + col);
    float4 w2 = *(const float4*)(W + (size_t)(k + 2) * D + col);
    float4 w3 = *(const float4*)(W + (size_t)(k + 3) * D + col);
#pragma unroll
    for (int r = 0; r < 8; ++r) {
      float4 a = *(const float4*)&As[rg * 8 + r][k];
      acc[r].x += a.x * w0.x + a.y * w1.x + a.z * w2.x + a.w * w3.x;
      acc[r].y += a.x * w0.y + a.y * w1.y + a.z * w2.y + a.w * w3.y;
      acc[r].z += a.x * w0.z + a.y * w1.z + a.z * w2.z + a.w * w3.z;
      acc[r].w += a.x * w0.w + a.y * w1.w + a.z * w2.w + a.w * w3.w;
    }
  }
#pragma unroll
  for (int r = 0; r < 8; ++r) {
    int row = row0 + rg * 8 + r;
    if (row < n) {
      float sc = rsqrtf(fmaxf((float)cout_[row], 1.f));
      ushort_t o[4] = { f2bf(acc[r].x * sc), f2bf(acc[r].y * sc),
                        f2bf(acc[r].z * sc), f2bf(acc[r].w * sc) };
      *(uint2*)(X + (size_t)row * D + col) = *(const uint2*)o;
    }
  }
}

// ---------------- aggregation (bf16 gather, 8-edge unroll) + bias + relu -> bf16 ----------------
__global__ __launch_bounds__(256) void agg_relu_kernel(const ushort_t* __restrict__ x,
    const int* __restrict__ rowptr, const int* __restrict__ csrc,
    const int* __restrict__ cin_, const float* __restrict__ bias,
    ushort_t* __restrict__ y, int n) {
  int node = blockIdx.x * 4 + (threadIdx.x >> 6);
  if (node >= n) return;
  int lane = threadIdx.x & 63;
  int beg = rowptr[node], end = rowptr[node + 1];
  float ax = 0.f, ay = 0.f;
  const ushort_t* xp = x + (size_t)(lane * 2);
  int e = beg;
  for (; e + 8 <= end; e += 8) {
    int s[8];
#pragma unroll
    for (int j = 0; j < 8; ++j) s[j] = csrc[e + j];
    ushort2 u[8];
#pragma unroll
    for (int j = 0; j < 8; ++j) u[j] = *(const ushort2*)(xp + (size_t)s[j] * D);
#pragma unroll
    for (int j = 0; j < 8; ++j) { ax += bf2f(u[j].x); ay += bf2f(u[j].y); }
  }
  if (e + 4 <= end) {
    int s[4];
#pragma unroll
    for (int j = 0; j < 4; ++j) s[j] = csrc[e + j];
    ushort2 u[4];
#pragma unroll
    for (int j = 0; j < 4; ++j) u[j] = *(const ushort2*)(xp + (size_t)s[j] * D);
#pragma unroll
    for (int j = 0; j < 4; ++j) { ax += bf2f(u[j].x); ay += bf2f(u[j].y); }
    e += 4;
  }
  for (; e < end; ++e) {
    int s = csrc[e];
    ushort2 u = *(const ushort2*)(xp + (size_t)s * D);
    ax += bf2f(u.x); ay += bf2f(u.y);
  }
  float wi = rsqrtf(fmaxf((float)cin_[node], 1.f));
  float2 bb = *(const float2*)(bias + lane * 2);
  ushort_t o[2] = { f2bf(fmaxf(ax * wi + bb.x, 0.f)), f2bf(fmaxf(ay * wi + bb.y, 0.f)) };
  *(unsigned*)(y + (size_t)node * D + lane * 2) = *(const unsigned*)o;
}

// ---------------- pooling (bf16 in) ----------------
__device__ int lower_bound_gid(const int* gid, int n, int g) {
  int lo = 0, hi = n;
  while (lo < hi) { int mid = (lo + hi) >> 1; if (gid[mid] < g) lo = mid + 1; else hi = mid; }
  return lo;
}

__global__ void pool_kernel(const ushort_t* __restrict__ x, const int* __restrict__ gid,
                            float* __restrict__ sums, int* __restrict__ counts, int n) {
  int g = blockIdx.x >> 3, part = blockIdx.x & 7;
  __shared__ int s_lo, s_hi;
  if (threadIdx.x == 0) {
    s_lo = lower_bound_gid(gid, n, g);
    s_hi = lower_bound_gid(gid, n, g + 1);
    if (part == 0) counts[g] = s_hi - s_lo;
  }
  __syncthreads();
  int lo = s_lo, hi = s_hi;
  int cnt = hi - lo;
  int per = (cnt + 7) >> 3;
  int a = lo + part * per;
  int bnd = min(a + per, hi);
  int t = threadIdx.x;
  float acc = 0.f;
  for (int i = a; i < bnd; ++i) acc += bf2f(x[(size_t)i * D + t]);
  atomicAdd(&sums[g * D + t], acc);
}

// ---------------- classifier ----------------
__global__ __launch_bounds__(128) void classifier_kernel(const float* __restrict__ sums,
    const int* __restrict__ counts, const float* __restrict__ Wc1, const float* __restrict__ bc1,
    const float* __restrict__ Wc2, const float* __restrict__ bc2, float* __restrict__ out) {
  __shared__ float hg[NG][D];
  __shared__ float hid[NG][D];
  int t = threadIdx.x;
#pragma unroll
  for (int g = 0; g < NG; ++g)
    hg[g][t] = sums[g * D + t] / fmaxf((float)counts[g], 1.f);
  __syncthreads();
  float acc[NG];
#pragma unroll
  for (int g = 0; g < NG; ++g) acc[g] = bc1[t];
  for (int k = 0; k < D; ++k) {
    float w = Wc1[k * D + t];
#pragma unroll
    for (int g = 0; g < NG; ++g) acc[g] += hg[g][k] * w;
  }
#pragma unroll
  for (int g = 0; g < NG; ++g) hid[g][t] = fmaxf(acc[g], 0.f);
  __syncthreads();
  for (int idx = t; idx < NG * NC; idx += 128) {
    int g = idx / NC, c = idx % NC;
    float a = bc2[c];
    for (int j = 0; j < D; ++j) a += hid[g][j] * Wc2[j * NC + c];
    out[idx] = a;
  }
}

extern "C" void kernel_launch(void* const* d_in, const int* in_sizes, int n_in,
                              void* d_out, int out_size, void* d_ws, size_t ws_size,
                              hipStream_t stream) {
  const float* h   = (const float*)d_in[0];
  const int* src   = (const int*)d_in[1];
  const int* dst   = (const int*)d_in[2];
  const int* gid   = (const int*)d_in[3];
  const float* W1  = (const float*)d_in[4];
  const float* b1  = (const float*)d_in[5];
  const float* W2  = (const float*)d_in[6];
  const float* b2  = (const float*)d_in[7];
  const float* W3  = (const float*)d_in[8];
  const float* b3  = (const float*)d_in[9];
  const float* W4  = (const float*)d_in[10];
  const float* b4  = (const float*)d_in[11];
  const float* Wc1 = (const float*)d_in[12];
  const float* bc1 = (const float*)d_in[13];
  const float* Wc2 = (const float*)d_in[14];
  const float* bc2 = (const float*)d_in[15];
  float* out = (float*)d_out;

  const int N = in_sizes[3];
  const int E = in_sizes[1];

  char* ws = (char*)d_ws;
  size_t off = 0;
  auto alloc = [&](size_t bytes) -> char* {
    char* p = ws + off;
    off = (off + bytes + 255) & ~(size_t)255;
    return p;
  };

  int* cnts     = (int*)alloc((size_t)2 * N * 4);   // cout | cursor(->in-degree)
  int* cout_    = cnts;
  int* cursor   = cnts + N;
  int* rowptr   = (int*)alloc((size_t)(N + 1) * 4);
  int* bsum     = (int*)alloc(1024);
  int* csrc     = (int*)alloc((size_t)E * 4);
  ushort_t* Xb  = (ushort_t*)alloc((size_t)N * D * 2);  // bf16 pre-agg (iout-scaled) features
  ushort_t* Yb  = (ushort_t*)alloc((size_t)N * D * 2);  // bf16 agg output; head doubles as rank[]
  float* sums   = (float*)alloc((size_t)(NG * D + NG) * 4);
  int* counts   = (int*)(sums + NG * D);
  int* rank     = (int*)Yb;  // overlay: consumed by passB before Yb first written

  hipMemsetAsync(cnts, 0, (size_t)2 * N * 4, stream);
  hipMemsetAsync(sums, 0, (size_t)(NG * D + NG) * 4, stream);

  int gE4 = (E / 4 + 255) / 256 + 1;
  int nb = (N + 1023) / 1024;
  int gAgg  = (N + 3) / 4;
  int gGemm = (N + 63) / 64;

  degree_kernel<<<gE4, 256, 0, stream>>>(src, dst, cout_, cursor, rank, E);
  scan1_kernel<<<nb, 256, 0, stream>>>(cursor, bsum, N);
  scan2_kernel<<<1, 64, 0, stream>>>(bsum, nb);
  scan3_kernel<<<nb, 256, 0, stream>>>(cursor, bsum, rowptr, N, E);
  passB_kernel<<<gE4, 256, 0, stream>>>(src, dst, rank, rowptr, csrc, E);

  // layer 1
  gemm_f32in_kernel<<<gGemm, 256, 0, stream>>>(h, W1, cout_, Xb, N);
  agg_relu_kernel<<<gAgg, 256, 0, stream>>>(Xb, rowptr, csrc, cursor, b1, Yb, N);
  // layer 2
  gemm_bf16in_kernel<<<gGemm, 256, 0, stream>>>(Yb, W2, cout_, Xb, N);
  agg_relu_kernel<<<gAgg, 256, 0, stream>>>(Xb, rowptr, csrc, cursor, b2, Yb, N);
  // layer 3
  gemm_bf16in_kernel<<<gGemm, 256, 0, stream>>>(Yb, W3, cout_, Xb, N);
  agg_relu_kernel<<<gAgg, 256, 0, stream>>>(Xb, rowptr, csrc, cursor, b3, Yb, N);
  // layer 4
  gemm_bf16in_kernel<<<gGemm, 256, 0, stream>>>(Yb, W4, cout_, Xb, N);
  agg_relu_kernel<<<gAgg, 256, 0, stream>>>(Xb, rowptr, csrc, cursor, b4, Yb, N);

  pool_kernel<<<NG * 8, 128, 0, stream>>>(Yb, gid, sums, counts, N);
  classifier_kernel<<<1, 128, 0, stream>>>(sums, counts, Wc1, bc1, Wc2, bc2, out);
}

// Round 6
// 1075.634 us; speedup vs baseline: 1.5986x; 1.0612x over previous
//
#include <hip/hip_runtime.h>

#define D 128
#define NG 32
#define NC 10

typedef unsigned short ushort_t;
typedef __attribute__((ext_vector_type(8))) short short8v;
typedef __attribute__((ext_vector_type(4))) float float4v;

__device__ __forceinline__ ushort_t f2bf(float x) {
  union { float f; unsigned u; } v; v.f = x;
  unsigned r = (v.u + 0x7FFF + ((v.u >> 16) & 1)) >> 16;
  return (ushort_t)r;
}
__device__ __forceinline__ float bf2f(ushort_t b) {
  union { unsigned u; float f; } v; v.u = ((unsigned)b) << 16;
  return v.f;
}

// ---------------- degree + tickets: ticket atomic (single) + replicated out-degree histogram ----------------
__global__ void degree_kernel(const int* __restrict__ src, const int* __restrict__ dst,
                              int* __restrict__ cout_r, int* __restrict__ cursor,
                              int* __restrict__ rank, int E, int n) {
  int* co = cout_r + (size_t)(blockIdx.x & 3) * n;
  int i = blockIdx.x * 256 + threadIdx.x;
  int e0 = i * 4;
  if (e0 + 4 <= E) {
    int4 s = *(const int4*)(src + e0);
    int4 d_ = *(const int4*)(dst + e0);
    int r0 = atomicAdd(&cursor[d_.x], 1);
    int r1 = atomicAdd(&cursor[d_.y], 1);
    int r2 = atomicAdd(&cursor[d_.z], 1);
    int r3 = atomicAdd(&cursor[d_.w], 1);
    atomicAdd(&co[s.x], 1);
    atomicAdd(&co[s.y], 1);
    atomicAdd(&co[s.z], 1);
    atomicAdd(&co[s.w], 1);
    *(int4*)(rank + e0) = make_int4(r0, r1, r2, r3);
  } else {
    for (int e = e0; e < E; ++e) {
      rank[e] = atomicAdd(&cursor[dst[e]], 1);
      atomicAdd(&co[src[e]], 1);
    }
  }
}

__global__ void sumdeg_kernel(const int* __restrict__ cout_r, int* __restrict__ cout_, int n) {
  int i = blockIdx.x * 256 + threadIdx.x;
  if (i < n)
    cout_[i] = cout_r[i] + cout_r[n + i] + cout_r[2 * (size_t)n + i] + cout_r[3 * (size_t)n + i];
}

// ---------------- scan ----------------
__global__ void scan1_kernel(const int* __restrict__ cnt, int* __restrict__ bsum, int n) {
  __shared__ int sdata[256];
  int base = blockIdx.x * 1024 + threadIdx.x * 4;
  int s = 0;
#pragma unroll
  for (int j = 0; j < 4; ++j) {
    int idx = base + j;
    if (idx < n) s += cnt[idx];
  }
  sdata[threadIdx.x] = s;
  __syncthreads();
  for (int off = 128; off > 0; off >>= 1) {
    if (threadIdx.x < off) sdata[threadIdx.x] += sdata[threadIdx.x + off];
    __syncthreads();
  }
  if (threadIdx.x == 0) bsum[blockIdx.x] = sdata[0];
}

__global__ void scan2_kernel(int* __restrict__ bsum, int nb) {
  if (blockIdx.x == 0 && threadIdx.x == 0) {
    int acc = 0;
    for (int i = 0; i < nb; ++i) { int v = bsum[i]; bsum[i] = acc; acc += v; }
  }
}

__global__ void scan3_kernel(const int* __restrict__ cnt, const int* __restrict__ bsum,
                             int* __restrict__ rowptr, int n, int e_total) {
  __shared__ int ss[256];
  int t = threadIdx.x;
  int idx0 = blockIdx.x * 1024 + t * 4;
  int v[4]; int ts = 0;
#pragma unroll
  for (int j = 0; j < 4; ++j) {
    v[j] = (idx0 + j < n) ? cnt[idx0 + j] : 0;
    ts += v[j];
  }
  ss[t] = ts;
  __syncthreads();
  for (int off = 1; off < 256; off <<= 1) {
    int add = 0;
    if (t >= off) add = ss[t - off];
    __syncthreads();
    if (t >= off) ss[t] += add;
    __syncthreads();
  }
  int excl = ss[t] - ts + bsum[blockIdx.x];
#pragma unroll
  for (int j = 0; j < 4; ++j) {
    int idx = idx0 + j;
    if (idx < n) rowptr[idx] = excl;
    excl += v[j];
  }
  if (blockIdx.x == 0 && t == 0) rowptr[n] = e_total;
}

// ---------------- pass B: atomic-free scatter ----------------
__global__ void passB_kernel(const int* __restrict__ src, const int* __restrict__ dst,
                             const int* __restrict__ rank, const int* __restrict__ rowptr,
                             int* __restrict__ csrc, int E) {
  int i = blockIdx.x * 256 + threadIdx.x;
  int e0 = i * 4;
  if (e0 + 4 <= E) {
    int4 s = *(const int4*)(src + e0);
    int4 d_ = *(const int4*)(dst + e0);
    int4 r = *(const int4*)(rank + e0);
    csrc[rowptr[d_.x] + r.x] = s.x;
    csrc[rowptr[d_.y] + r.y] = s.y;
    csrc[rowptr[d_.z] + r.z] = s.z;
    csrc[rowptr[d_.w] + r.w] = s.w;
  } else {
    for (int e = e0; e < E; ++e)
      csrc[rowptr[dst[e]] + rank[e]] = src[e];
  }
}

// ---------------- conversions ----------------
__global__ void cvt_h_kernel(const float* __restrict__ h, ushort_t* __restrict__ hb, long total) {
  long i4 = ((long)blockIdx.x * 256 + threadIdx.x) * 4;
  if (i4 + 4 <= total) {
    float4 v = *(const float4*)(h + i4);
    ushort_t o[4] = { f2bf(v.x), f2bf(v.y), f2bf(v.z), f2bf(v.w) };
    *(uint2*)(hb + i4) = *(const uint2*)o;
  } else {
    for (long i = i4; i < total; ++i) hb[i] = f2bf(h[i]);
  }
}

// 4 blocks: transpose + convert each W -> Wt[c][k] bf16
__global__ void cvt_w_kernel(const float* __restrict__ W1, const float* __restrict__ W2,
                             const float* __restrict__ W3, const float* __restrict__ W4,
                             ushort_t* __restrict__ Wt) {
  const float* Ws[4] = { W1, W2, W3, W4 };
  const float* W = Ws[blockIdx.x];
  ushort_t* o = Wt + (size_t)blockIdx.x * D * D;
  for (int idx = threadIdx.x; idx < D * D; idx += 256) {
    int c = idx >> 7, k = idx & 127;
    o[c * D + k] = f2bf(W[k * D + c]);
  }
}

// ---------------- MFMA GEMM: X[n,128] = bf16( iout * (A @ W) ), A bf16, Wt = W^T bf16 ----------------
// block = 256 thr = 4 waves; wave covers 16 rows x 128 cols; K=128 in 4 steps of 32.
__global__ __launch_bounds__(256) void gemm_mfma_kernel(const ushort_t* __restrict__ A,
    const ushort_t* __restrict__ Wt, const int* __restrict__ cout_,
    ushort_t* __restrict__ X, int n) {
  int wave = threadIdx.x >> 6;
  int lane = threadIdx.x & 63;
  int g = lane >> 4;          // k-group 0..3
  int lr = lane & 15;
  int rowbase = blockIdx.x * 64 + wave * 16;
  int arow = rowbase + lr;
  int arow_c = arow < n ? arow : (n - 1);
  const ushort_t* Ap = A + (size_t)arow_c * D + g * 8;

  short8v afrag[4];
#pragma unroll
  for (int ks = 0; ks < 4; ++ks)
    afrag[ks] = *(const short8v*)(Ap + ks * 32);

  float4v acc[8];
#pragma unroll
  for (int ct = 0; ct < 8; ++ct)
#pragma unroll
    for (int r = 0; r < 4; ++r) acc[ct][r] = 0.f;

#pragma unroll
  for (int ct = 0; ct < 8; ++ct) {
    const ushort_t* bp = Wt + (size_t)(ct * 16 + lr) * D + g * 8;
#pragma unroll
    for (int ks = 0; ks < 4; ++ks) {
      short8v bfrag = *(const short8v*)(bp + ks * 32);
      acc[ct] = __builtin_amdgcn_mfma_f32_16x16x32_bf16(afrag[ks], bfrag, acc[ct], 0, 0, 0);
    }
  }

  // epilogue: D row = g*4 + r (within wave tile), col = ct*16 + lr
  float scv[4];
  bool rok[4];
#pragma unroll
  for (int r = 0; r < 4; ++r) {
    int grow = rowbase + g * 4 + r;
    rok[r] = grow < n;
    int gc = rok[r] ? grow : (n - 1);
    scv[r] = rsqrtf(fmaxf((float)cout_[gc], 1.f));
  }
#pragma unroll
  for (int ct = 0; ct < 8; ++ct) {
#pragma unroll
    for (int r = 0; r < 4; ++r) {
      int grow = rowbase + g * 4 + r;
      if (rok[r]) X[(size_t)grow * D + ct * 16 + lr] = f2bf(acc[ct][r] * scv[r]);
    }
  }
}

// ---------------- aggregation (bf16 gather, 8-edge unroll) + bias + relu -> bf16 ----------------
__global__ __launch_bounds__(256) void agg_relu_kernel(const ushort_t* __restrict__ x,
    const int* __restrict__ rowptr, const int* __restrict__ csrc,
    const int* __restrict__ cin_, const float* __restrict__ bias,
    ushort_t* __restrict__ y, int n) {
  int node = blockIdx.x * 4 + (threadIdx.x >> 6);
  if (node >= n) return;
  int lane = threadIdx.x & 63;
  int beg = rowptr[node], end = rowptr[node + 1];
  float ax = 0.f, ay = 0.f;
  const ushort_t* xp = x + (size_t)(lane * 2);
  int e = beg;
  for (; e + 8 <= end; e += 8) {
    int s[8];
#pragma unroll
    for (int j = 0; j < 8; ++j) s[j] = csrc[e + j];
    ushort2 u[8];
#pragma unroll
    for (int j = 0; j < 8; ++j) u[j] = *(const ushort2*)(xp + (size_t)s[j] * D);
#pragma unroll
    for (int j = 0; j < 8; ++j) { ax += bf2f(u[j].x); ay += bf2f(u[j].y); }
  }
  if (e + 4 <= end) {
    int s[4];
#pragma unroll
    for (int j = 0; j < 4; ++j) s[j] = csrc[e + j];
    ushort2 u[4];
#pragma unroll
    for (int j = 0; j < 4; ++j) u[j] = *(const ushort2*)(xp + (size_t)s[j] * D);
#pragma unroll
    for (int j = 0; j < 4; ++j) { ax += bf2f(u[j].x); ay += bf2f(u[j].y); }
    e += 4;
  }
  for (; e < end; ++e) {
    int s = csrc[e];
    ushort2 u = *(const ushort2*)(xp + (size_t)s * D);
    ax += bf2f(u.x); ay += bf2f(u.y);
  }
  float wi = rsqrtf(fmaxf((float)cin_[node], 1.f));
  float2 bb = *(const float2*)(bias + lane * 2);
  ushort_t o[2] = { f2bf(fmaxf(ax * wi + bb.x, 0.f)), f2bf(fmaxf(ay * wi + bb.y, 0.f)) };
  *(unsigned*)(y + (size_t)node * D + lane * 2) = *(const unsigned*)o;
}

// ---------------- pooling (bf16 in) ----------------
__device__ int lower_bound_gid(const int* gid, int n, int g) {
  int lo = 0, hi = n;
  while (lo < hi) { int mid = (lo + hi) >> 1; if (gid[mid] < g) lo = mid + 1; else hi = mid; }
  return lo;
}

__global__ void pool_kernel(const ushort_t* __restrict__ x, const int* __restrict__ gid,
                            float* __restrict__ sums, int* __restrict__ counts, int n) {
  int g = blockIdx.x >> 3, part = blockIdx.x & 7;
  __shared__ int s_lo, s_hi;
  if (threadIdx.x == 0) {
    s_lo = lower_bound_gid(gid, n, g);
    s_hi = lower_bound_gid(gid, n, g + 1);
    if (part == 0) counts[g] = s_hi - s_lo;
  }
  __syncthreads();
  int lo = s_lo, hi = s_hi;
  int cnt = hi - lo;
  int per = (cnt + 7) >> 3;
  int a = lo + part * per;
  int bnd = min(a + per, hi);
  int t = threadIdx.x;
  float acc = 0.f;
  for (int i = a; i < bnd; ++i) acc += bf2f(x[(size_t)i * D + t]);
  atomicAdd(&sums[g * D + t], acc);
}

// ---------------- classifier ----------------
__global__ __launch_bounds__(128) void classifier_kernel(const float* __restrict__ sums,
    const int* __restrict__ counts, const float* __restrict__ Wc1, const float* __restrict__ bc1,
    const float* __restrict__ Wc2, const float* __restrict__ bc2, float* __restrict__ out) {
  __shared__ float hg[NG][D];
  __shared__ float hid[NG][D];
  int t = threadIdx.x;
#pragma unroll
  for (int g = 0; g < NG; ++g)
    hg[g][t] = sums[g * D + t] / fmaxf((float)counts[g], 1.f);
  __syncthreads();
  float acc[NG];
#pragma unroll
  for (int g = 0; g < NG; ++g) acc[g] = bc1[t];
  for (int k = 0; k < D; ++k) {
    float w = Wc1[k * D + t];
#pragma unroll
    for (int g = 0; g < NG; ++g) acc[g] += hg[g][k] * w;
  }
#pragma unroll
  for (int g = 0; g < NG; ++g) hid[g][t] = fmaxf(acc[g], 0.f);
  __syncthreads();
  for (int idx = t; idx < NG * NC; idx += 128) {
    int g = idx / NC, c = idx % NC;
    float a = bc2[c];
    for (int j = 0; j < D; ++j) a += hid[g][j] * Wc2[j * NC + c];
    out[idx] = a;
  }
}

extern "C" void kernel_launch(void* const* d_in, const int* in_sizes, int n_in,
                              void* d_out, int out_size, void* d_ws, size_t ws_size,
                              hipStream_t stream) {
  const float* h   = (const float*)d_in[0];
  const int* src   = (const int*)d_in[1];
  const int* dst   = (const int*)d_in[2];
  const int* gid   = (const int*)d_in[3];
  const float* W1  = (const float*)d_in[4];
  const float* b1  = (const float*)d_in[5];
  const float* W2  = (const float*)d_in[6];
  const float* b2  = (const float*)d_in[7];
  const float* W3  = (const float*)d_in[8];
  const float* b3  = (const float*)d_in[9];
  const float* W4  = (const float*)d_in[10];
  const float* b4  = (const float*)d_in[11];
  const float* Wc1 = (const float*)d_in[12];
  const float* bc1 = (const float*)d_in[13];
  const float* Wc2 = (const float*)d_in[14];
  const float* bc2 = (const float*)d_in[15];
  float* out = (float*)d_out;

  const int N = in_sizes[3];
  const int E = in_sizes[1];

  char* ws = (char*)d_ws;
  size_t off = 0;
  auto alloc = [&](size_t bytes) -> char* {
    char* p = ws + off;
    off = (off + bytes + 255) & ~(size_t)255;
    return p;
  };

  int* cnts     = (int*)alloc((size_t)5 * N * 4);   // cout_r[4N] | cursor[N]
  int* cout_r   = cnts;
  int* cursor   = cnts + (size_t)4 * N;
  int* cout_    = (int*)alloc((size_t)N * 4);       // summed out-degree (no memset needed)
  int* rowptr   = (int*)alloc((size_t)(N + 1) * 4);
  int* bsum     = (int*)alloc(1024);
  int* csrc     = (int*)alloc((size_t)E * 4);
  ushort_t* Wt  = (ushort_t*)alloc((size_t)4 * D * D * 2);
  ushort_t* Xb  = (ushort_t*)alloc((size_t)N * D * 2);  // bf16 pre-agg (iout-scaled) features
  ushort_t* Yb  = (ushort_t*)alloc((size_t)N * D * 2);  // bf16 agg output; head: rank[], then Hb
  float* sums   = (float*)alloc((size_t)(NG * D + NG) * 4);
  int* counts   = (int*)(sums + NG * D);
  int* rank     = (int*)Yb;        // overlay 1: consumed by passB
  ushort_t* Hb  = Yb;              // overlay 2: bf16(h), written after passB, dead after gemm1

  hipMemsetAsync(cnts, 0, (size_t)5 * N * 4, stream);
  hipMemsetAsync(sums, 0, (size_t)(NG * D + NG) * 4, stream);

  int gE4 = (E / 4 + 255) / 256 + 1;
  int gN  = (N + 255) / 256;
  int nb  = (N + 1023) / 1024;
  int gAgg  = (N + 3) / 4;
  int gGemm = (N + 63) / 64;
  long totalH = (long)N * D;
  int gCvt = (int)((totalH / 4 + 255) / 256) + 1;

  degree_kernel<<<gE4, 256, 0, stream>>>(src, dst, cout_r, cursor, rank, E, N);
  sumdeg_kernel<<<gN, 256, 0, stream>>>(cout_r, cout_, N);
  scan1_kernel<<<nb, 256, 0, stream>>>(cursor, bsum, N);
  scan2_kernel<<<1, 64, 0, stream>>>(bsum, nb);
  scan3_kernel<<<nb, 256, 0, stream>>>(cursor, bsum, rowptr, N, E);
  passB_kernel<<<gE4, 256, 0, stream>>>(src, dst, rank, rowptr, csrc, E);

  cvt_w_kernel<<<4, 256, 0, stream>>>(W1, W2, W3, W4, Wt);
  cvt_h_kernel<<<gCvt, 256, 0, stream>>>(h, Hb, totalH);

  // layer 1
  gemm_mfma_kernel<<<gGemm, 256, 0, stream>>>(Hb, Wt, cout_, Xb, N);
  agg_relu_kernel<<<gAgg, 256, 0, stream>>>(Xb, rowptr, csrc, cursor, b1, Yb, N);
  // layer 2
  gemm_mfma_kernel<<<gGemm, 256, 0, stream>>>(Yb, Wt + (size_t)1 * D * D, cout_, Xb, N);
  agg_relu_kernel<<<gAgg, 256, 0, stream>>>(Xb, rowptr, csrc, cursor, b2, Yb, N);
  // layer 3
  gemm_mfma_kernel<<<gGemm, 256, 0, stream>>>(Yb, Wt + (size_t)2 * D * D, cout_, Xb, N);
  agg_relu_kernel<<<gAgg, 256, 0, stream>>>(Xb, rowptr, csrc, cursor, b3, Yb, N);
  // layer 4
  gemm_mfma_kernel<<<gGemm, 256, 0, stream>>>(Yb, Wt + (size_t)3 * D * D, cout_, Xb, N);
  agg_relu_kernel<<<gAgg, 256, 0, stream>>>(Xb, rowptr, csrc, cursor, b4, Yb, N);

  pool_kernel<<<NG * 8, 128, 0, stream>>>(Yb, gid, sums, counts, N);
  classifier_kernel<<<1, 128, 0, stream>>>(sums, counts, Wc1, bc1, Wc2, bc2, out);
}

// Round 7
// 955.850 us; speedup vs baseline: 1.7989x; 1.1253x over previous
//
#include <hip/hip_runtime.h>

#define D 128
#define NG 32
#define NC 10

typedef unsigned short ushort_t;
typedef __attribute__((ext_vector_type(8))) short short8v;
typedef __attribute__((ext_vector_type(4))) float float4v;
typedef __attribute__((ext_vector_type(2))) float float2v;

__device__ __forceinline__ ushort_t f2bf(float x) {
  union { float f; unsigned u; } v; v.f = x;
  unsigned r = (v.u + 0x7FFF + ((v.u >> 16) & 1)) >> 16;
  return (ushort_t)r;
}
__device__ __forceinline__ float bf2f(ushort_t b) {
  union { unsigned u; float f; } v; v.u = ((unsigned)b) << 16;
  return v.f;
}

// ---------------- degree + tickets: 4 edges/thread (R5 form — atomic-pipe bound) ----------------
__global__ void degree_kernel(const int* __restrict__ src, const int* __restrict__ dst,
                              int* __restrict__ cout_, int* __restrict__ cursor,
                              int* __restrict__ rank, int E) {
  int i = blockIdx.x * 256 + threadIdx.x;
  int e0 = i * 4;
  if (e0 + 4 <= E) {
    int4 s = *(const int4*)(src + e0);
    int4 d_ = *(const int4*)(dst + e0);
    int r0 = atomicAdd(&cursor[d_.x], 1);
    int r1 = atomicAdd(&cursor[d_.y], 1);
    int r2 = atomicAdd(&cursor[d_.z], 1);
    int r3 = atomicAdd(&cursor[d_.w], 1);
    atomicAdd(&cout_[s.x], 1);
    atomicAdd(&cout_[s.y], 1);
    atomicAdd(&cout_[s.z], 1);
    atomicAdd(&cout_[s.w], 1);
    *(int4*)(rank + e0) = make_int4(r0, r1, r2, r3);
  } else {
    for (int e = e0; e < E; ++e) {
      rank[e] = atomicAdd(&cursor[dst[e]], 1);
      atomicAdd(&cout_[src[e]], 1);
    }
  }
}

// ---------------- scan ----------------
__global__ void scan1_kernel(const int* __restrict__ cnt, int* __restrict__ bsum, int n) {
  __shared__ int sdata[256];
  int base = blockIdx.x * 1024 + threadIdx.x * 4;
  int s = 0;
#pragma unroll
  for (int j = 0; j < 4; ++j) {
    int idx = base + j;
    if (idx < n) s += cnt[idx];
  }
  sdata[threadIdx.x] = s;
  __syncthreads();
  for (int off = 128; off > 0; off >>= 1) {
    if (threadIdx.x < off) sdata[threadIdx.x] += sdata[threadIdx.x + off];
    __syncthreads();
  }
  if (threadIdx.x == 0) bsum[blockIdx.x] = sdata[0];
}

__global__ void scan2_kernel(int* __restrict__ bsum, int nb) {
  if (blockIdx.x == 0 && threadIdx.x == 0) {
    int acc = 0;
    for (int i = 0; i < nb; ++i) { int v = bsum[i]; bsum[i] = acc; acc += v; }
  }
}

__global__ void scan3_kernel(const int* __restrict__ cnt, const int* __restrict__ bsum,
                             int* __restrict__ rowptr, int n, int e_total) {
  __shared__ int ss[256];
  int t = threadIdx.x;
  int idx0 = blockIdx.x * 1024 + t * 4;
  int v[4]; int ts = 0;
#pragma unroll
  for (int j = 0; j < 4; ++j) {
    v[j] = (idx0 + j < n) ? cnt[idx0 + j] : 0;
    ts += v[j];
  }
  ss[t] = ts;
  __syncthreads();
  for (int off = 1; off < 256; off <<= 1) {
    int add = 0;
    if (t >= off) add = ss[t - off];
    __syncthreads();
    if (t >= off) ss[t] += add;
    __syncthreads();
  }
  int excl = ss[t] - ts + bsum[blockIdx.x];
#pragma unroll
  for (int j = 0; j < 4; ++j) {
    int idx = idx0 + j;
    if (idx < n) rowptr[idx] = excl;
    excl += v[j];
  }
  if (blockIdx.x == 0 && t == 0) rowptr[n] = e_total;
}

// ---------------- pass B: atomic-free scatter ----------------
__global__ void passB_kernel(const int* __restrict__ src, const int* __restrict__ dst,
                             const int* __restrict__ rank, const int* __restrict__ rowptr,
                             int* __restrict__ csrc, int E) {
  int i = blockIdx.x * 256 + threadIdx.x;
  int e0 = i * 4;
  if (e0 + 4 <= E) {
    int4 s = *(const int4*)(src + e0);
    int4 d_ = *(const int4*)(dst + e0);
    int4 r = *(const int4*)(rank + e0);
    csrc[rowptr[d_.x] + r.x] = s.x;
    csrc[rowptr[d_.y] + r.y] = s.y;
    csrc[rowptr[d_.z] + r.z] = s.z;
    csrc[rowptr[d_.w] + r.w] = s.w;
  } else {
    for (int e = e0; e < E; ++e)
      csrc[rowptr[dst[e]] + rank[e]] = src[e];
  }
}

// ---------------- conversions ----------------
__global__ void cvt_h_kernel(const float* __restrict__ h, ushort_t* __restrict__ hb, long total) {
  long i4 = ((long)blockIdx.x * 256 + threadIdx.x) * 4;
  if (i4 + 4 <= total) {
    float4 v = *(const float4*)(h + i4);
    ushort_t o[4] = { f2bf(v.x), f2bf(v.y), f2bf(v.z), f2bf(v.w) };
    *(uint2*)(hb + i4) = *(const uint2*)o;
  } else {
    for (long i = i4; i < total; ++i) hb[i] = f2bf(h[i]);
  }
}

// 4 blocks: transpose + convert each W -> Wt[c][k] bf16
__global__ void cvt_w_kernel(const float* __restrict__ W1, const float* __restrict__ W2,
                             const float* __restrict__ W3, const float* __restrict__ W4,
                             ushort_t* __restrict__ Wt) {
  const float* Ws[4] = { W1, W2, W3, W4 };
  const float* W = Ws[blockIdx.x];
  ushort_t* o = Wt + (size_t)blockIdx.x * D * D;
  for (int idx = threadIdx.x; idx < D * D; idx += 256) {
    int c = idx >> 7, k = idx & 127;
    o[c * D + k] = f2bf(W[k * D + c]);
  }
}

// ---------------- MFMA GEMM: X[n,128] = fp8( iout * (A @ W) ), A bf16, Wt = W^T bf16 ----------------
__global__ __launch_bounds__(256) void gemm_mfma_kernel(const ushort_t* __restrict__ A,
    const ushort_t* __restrict__ Wt, const int* __restrict__ cout_,
    unsigned char* __restrict__ X, int n) {
  int wave = threadIdx.x >> 6;
  int lane = threadIdx.x & 63;
  int g = lane >> 4;          // k-group 0..3
  int lr = lane & 15;
  int rowbase = blockIdx.x * 64 + wave * 16;
  int arow = rowbase + lr;
  int arow_c = arow < n ? arow : (n - 1);
  const ushort_t* Ap = A + (size_t)arow_c * D + g * 8;

  short8v afrag[4];
#pragma unroll
  for (int ks = 0; ks < 4; ++ks)
    afrag[ks] = *(const short8v*)(Ap + ks * 32);

  float4v acc[8];
#pragma unroll
  for (int ct = 0; ct < 8; ++ct)
#pragma unroll
    for (int r = 0; r < 4; ++r) acc[ct][r] = 0.f;

#pragma unroll
  for (int ct = 0; ct < 8; ++ct) {
    const ushort_t* bp = Wt + (size_t)(ct * 16 + lr) * D + g * 8;
#pragma unroll
    for (int ks = 0; ks < 4; ++ks) {
      short8v bfrag = *(const short8v*)(bp + ks * 32);
      acc[ct] = __builtin_amdgcn_mfma_f32_16x16x32_bf16(afrag[ks], bfrag, acc[ct], 0, 0, 0);
    }
  }

  float scv[4];
  bool rok[4];
#pragma unroll
  for (int r = 0; r < 4; ++r) {
    int grow = rowbase + g * 4 + r;
    rok[r] = grow < n;
    int gc = rok[r] ? grow : (n - 1);
    scv[r] = rsqrtf(fmaxf((float)cout_[gc], 1.f));
  }
#pragma unroll
  for (int ct = 0; ct < 8; ++ct) {
#pragma unroll
    for (int r = 0; r < 4; ++r) {
      int grow = rowbase + g * 4 + r;
      if (rok[r]) {
        int p = __builtin_amdgcn_cvt_pk_fp8_f32(acc[ct][r] * scv[r], 0.f, 0, false);
        X[(size_t)grow * D + ct * 16 + lr] = (unsigned char)(p & 0xff);
      }
    }
  }
}

// ---------------- aggregation (fp8 gather, 8-edge unroll) + bias + relu -> bf16 ----------------
__global__ __launch_bounds__(256) void agg_relu_kernel(const unsigned char* __restrict__ x,
    const int* __restrict__ rowptr, const int* __restrict__ csrc,
    const int* __restrict__ cin_, const float* __restrict__ bias,
    ushort_t* __restrict__ y, int n) {
  int node = blockIdx.x * 4 + (threadIdx.x >> 6);
  if (node >= n) return;
  int lane = threadIdx.x & 63;
  int beg = rowptr[node], end = rowptr[node + 1];
  float ax = 0.f, ay = 0.f;
  const unsigned char* xp = x + lane * 2;
  int e = beg;
  for (; e + 8 <= end; e += 8) {
    int s[8];
#pragma unroll
    for (int j = 0; j < 8; ++j) s[j] = csrc[e + j];
    ushort_t u[8];
#pragma unroll
    for (int j = 0; j < 8; ++j) u[j] = *(const ushort_t*)(xp + (size_t)s[j] * D);
#pragma unroll
    for (int j = 0; j < 8; ++j) {
      float2v f = __builtin_amdgcn_cvt_pk_f32_fp8((unsigned)u[j], false);
      ax += f[0]; ay += f[1];
    }
  }
  if (e + 4 <= end) {
    int s[4];
#pragma unroll
    for (int j = 0; j < 4; ++j) s[j] = csrc[e + j];
    ushort_t u[4];
#pragma unroll
    for (int j = 0; j < 4; ++j) u[j] = *(const ushort_t*)(xp + (size_t)s[j] * D);
#pragma unroll
    for (int j = 0; j < 4; ++j) {
      float2v f = __builtin_amdgcn_cvt_pk_f32_fp8((unsigned)u[j], false);
      ax += f[0]; ay += f[1];
    }
    e += 4;
  }
  for (; e < end; ++e) {
    int s = csrc[e];
    ushort_t u = *(const ushort_t*)(xp + (size_t)s * D);
    float2v f = __builtin_amdgcn_cvt_pk_f32_fp8((unsigned)u, false);
    ax += f[0]; ay += f[1];
  }
  float wi = rsqrtf(fmaxf((float)cin_[node], 1.f));
  float2 bb = *(const float2*)(bias + lane * 2);
  ushort_t o[2] = { f2bf(fmaxf(ax * wi + bb.x, 0.f)), f2bf(fmaxf(ay * wi + bb.y, 0.f)) };
  *(unsigned*)(y + (size_t)node * D + lane * 2) = *(const unsigned*)o;
}

// ---------------- pooling (bf16 in) ----------------
__device__ int lower_bound_gid(const int* gid, int n, int g) {
  int lo = 0, hi = n;
  while (lo < hi) { int mid = (lo + hi) >> 1; if (gid[mid] < g) lo = mid + 1; else hi = mid; }
  return lo;
}

__global__ void pool_kernel(const ushort_t* __restrict__ x, const int* __restrict__ gid,
                            float* __restrict__ sums, int* __restrict__ counts, int n) {
  int g = blockIdx.x >> 3, part = blockIdx.x & 7;
  __shared__ int s_lo, s_hi;
  if (threadIdx.x == 0) {
    s_lo = lower_bound_gid(gid, n, g);
    s_hi = lower_bound_gid(gid, n, g + 1);
    if (part == 0) counts[g] = s_hi - s_lo;
  }
  __syncthreads();
  int lo = s_lo, hi = s_hi;
  int cnt = hi - lo;
  int per = (cnt + 7) >> 3;
  int a = lo + part * per;
  int bnd = min(a + per, hi);
  int t = threadIdx.x;
  float acc = 0.f;
  for (int i = a; i < bnd; ++i) acc += bf2f(x[(size_t)i * D + t]);
  atomicAdd(&sums[g * D + t], acc);
}

// ---------------- classifier ----------------
__global__ __launch_bounds__(128) void classifier_kernel(const float* __restrict__ sums,
    const int* __restrict__ counts, const float* __restrict__ Wc1, const float* __restrict__ bc1,
    const float* __restrict__ Wc2, const float* __restrict__ bc2, float* __restrict__ out) {
  __shared__ float hg[NG][D];
  __shared__ float hid[NG][D];
  int t = threadIdx.x;
#pragma unroll
  for (int g = 0; g < NG; ++g)
    hg[g][t] = sums[g * D + t] / fmaxf((float)counts[g], 1.f);
  __syncthreads();
  float acc[NG];
#pragma unroll
  for (int g = 0; g < NG; ++g) acc[g] = bc1[t];
  for (int k = 0; k < D; ++k) {
    float w = Wc1[k * D + t];
#pragma unroll
    for (int g = 0; g < NG; ++g) acc[g] += hg[g][k] * w;
  }
#pragma unroll
  for (int g = 0; g < NG; ++g) hid[g][t] = fmaxf(acc[g], 0.f);
  __syncthreads();
  for (int idx = t; idx < NG * NC; idx += 128) {
    int g = idx / NC, c = idx % NC;
    float a = bc2[c];
    for (int j = 0; j < D; ++j) a += hid[g][j] * Wc2[j * NC + c];
    out[idx] = a;
  }
}

extern "C" void kernel_launch(void* const* d_in, const int* in_sizes, int n_in,
                              void* d_out, int out_size, void* d_ws, size_t ws_size,
                              hipStream_t stream) {
  const float* h   = (const float*)d_in[0];
  const int* src   = (const int*)d_in[1];
  const int* dst   = (const int*)d_in[2];
  const int* gid   = (const int*)d_in[3];
  const float* W1  = (const float*)d_in[4];
  const float* b1  = (const float*)d_in[5];
  const float* W2  = (const float*)d_in[6];
  const float* b2  = (const float*)d_in[7];
  const float* W3  = (const float*)d_in[8];
  const float* b3  = (const float*)d_in[9];
  const float* W4  = (const float*)d_in[10];
  const float* b4  = (const float*)d_in[11];
  const float* Wc1 = (const float*)d_in[12];
  const float* bc1 = (const float*)d_in[13];
  const float* Wc2 = (const float*)d_in[14];
  const float* bc2 = (const float*)d_in[15];
  float* out = (float*)d_out;

  const int N = in_sizes[3];
  const int E = in_sizes[1];

  char* ws = (char*)d_ws;
  size_t off = 0;
  auto alloc = [&](size_t bytes) -> char* {
    char* p = ws + off;
    off = (off + bytes + 255) & ~(size_t)255;
    return p;
  };

  int* cnts     = (int*)alloc((size_t)2 * N * 4);   // cout | cursor(->in-degree)
  int* cout_    = cnts;
  int* cursor   = cnts + N;
  int* rowptr   = (int*)alloc((size_t)(N + 1) * 4);
  int* bsum     = (int*)alloc(1024);
  int* csrc     = (int*)alloc((size_t)E * 4);
  ushort_t* Wt  = (ushort_t*)alloc((size_t)4 * D * D * 2);
  unsigned char* Xb = (unsigned char*)alloc((size_t)N * D);  // fp8 pre-agg (iout-scaled)
  ushort_t* Yb  = (ushort_t*)alloc((size_t)N * D * 2);       // bf16 agg out; head: rank[] then Hb
  float* sums   = (float*)alloc((size_t)(NG * D + NG) * 4);
  int* counts   = (int*)(sums + NG * D);
  int* rank     = (int*)Yb;        // overlay 1: consumed by passB
  ushort_t* Hb  = Yb;              // overlay 2: bf16(h), written after passB, dead after gemm1

  hipMemsetAsync(cnts, 0, (size_t)2 * N * 4, stream);
  hipMemsetAsync(sums, 0, (size_t)(NG * D + NG) * 4, stream);

  int gE4 = (E / 4 + 255) / 256 + 1;
  int nb  = (N + 1023) / 1024;
  int gAgg  = (N + 3) / 4;
  int gGemm = (N + 63) / 64;
  long totalH = (long)N * D;
  int gCvt = (int)((totalH / 4 + 255) / 256) + 1;

  degree_kernel<<<gE4, 256, 0, stream>>>(src, dst, cout_, cursor, rank, E);
  scan1_kernel<<<nb, 256, 0, stream>>>(cursor, bsum, N);
  scan2_kernel<<<1, 64, 0, stream>>>(bsum, nb);
  scan3_kernel<<<nb, 256, 0, stream>>>(cursor, bsum, rowptr, N, E);
  passB_kernel<<<gE4, 256, 0, stream>>>(src, dst, rank, rowptr, csrc, E);

  cvt_w_kernel<<<4, 256, 0, stream>>>(W1, W2, W3, W4, Wt);
  cvt_h_kernel<<<gCvt, 256, 0, stream>>>(h, Hb, totalH);

  // layer 1
  gemm_mfma_kernel<<<gGemm, 256, 0, stream>>>(Hb, Wt, cout_, Xb, N);
  agg_relu_kernel<<<gAgg, 256, 0, stream>>>(Xb, rowptr, csrc, cursor, b1, Yb, N);
  // layer 2
  gemm_mfma_kernel<<<gGemm, 256, 0, stream>>>(Yb, Wt + (size_t)1 * D * D, cout_, Xb, N);
  agg_relu_kernel<<<gAgg, 256, 0, stream>>>(Xb, rowptr, csrc, cursor, b2, Yb, N);
  // layer 3
  gemm_mfma_kernel<<<gGemm, 256, 0, stream>>>(Yb, Wt + (size_t)2 * D * D, cout_, Xb, N);
  agg_relu_kernel<<<gAgg, 256, 0, stream>>>(Xb, rowptr, csrc, cursor, b3, Yb, N);
  // layer 4
  gemm_mfma_kernel<<<gGemm, 256, 0, stream>>>(Yb, Wt + (size_t)3 * D * D, cout_, Xb, N);
  agg_relu_kernel<<<gAgg, 256, 0, stream>>>(Xb, rowptr, csrc, cursor, b4, Yb, N);

  pool_kernel<<<NG * 8, 128, 0, stream>>>(Yb, gid, sums, counts, N);
  classifier_kernel<<<1, 128, 0, stream>>>(sums, counts, Wc1, bc1, Wc2, bc2, out);
}